// Round 3
// baseline (821.414 us; speedup 1.0000x reference)
//
#include <hip/hip_runtime.h>
#include <math.h>

#define NB 4
#define NN 1024
#define ND 128
#define NUM_IN 64
#define F_EPS 1e-8f
#define BT_SCALE 1.8477590650225735f      // sqrt(2+sqrt(2))
#define INV_SQRT_D 0.08838834764831844f   // 1/sqrt(128)
#define BASELINE (1.0f/1025.0f)
#define OUT_STRIDE 256
#define A_OFF 1048576                     // floats: NB*NN*OUT_STRIDE

__device__ __forceinline__ float buntanh_f(float x) {
    return BT_SCALE * (0.5f * x + 0.5f * tanhf(x));
}
__device__ __forceinline__ float wave_sum(float v) {
    #pragma unroll
    for (int off = 32; off > 0; off >>= 1) v += __shfl_xor(v, off, 64);
    return v;
}
__device__ __forceinline__ float bflo(unsigned u) { return __uint_as_float(u << 16); }
__device__ __forceinline__ float bfhi(unsigned u) { return __uint_as_float(u & 0xffff0000u); }
__device__ __forceinline__ unsigned bf_rne(float f) {
    unsigned x = __float_as_uint(f);
    return (x + 0x7fffu + ((x >> 16) & 1u)) >> 16;
}
__device__ __forceinline__ unsigned bf_pack(float lo, float hi) {
    return bf_rne(lo) | (bf_rne(hi) << 16);
}

// ---------- K1: per-node matvecs (w1,w2,w3 fused) -> prediction, K, Q ----------
__global__ __launch_bounds__(256, 4) void qkp_kernel(
    const float* __restrict__ state,
    const float* __restrict__ w1,
    const float* __restrict__ w2,
    const float* __restrict__ w3,
    float* __restrict__ dout,
    float* __restrict__ Qg,
    float* __restrict__ Kg)
{
    const int node = blockIdx.x;             // b*NN + n, 0..4095
    __shared__ float s_state[ND];
    __shared__ float4 red[3][8][32];

    const int t = threadIdx.x;
    if (t < 32) *(float4*)&s_state[4*t] =
        *(const float4*)(state + ((size_t)node << 7) + 4*t);
    __syncthreads();

    const int g = t >> 5, m = t & 31;

    auto do_mat = [&](const float* wbase, int q) {
        const float4* w4 = (const float4*)(wbase + ((size_t)node << 14));
        float4 wv[16];
        #pragma unroll
        for (int i = 0; i < 16; ++i) wv[i] = w4[i*256 + t];
        float4 acc = make_float4(0.f, 0.f, 0.f, 0.f);
        #pragma unroll
        for (int i = 0; i < 16; ++i) {
            const float s = s_state[i*8 + g];
            acc.x += s*wv[i].x; acc.y += s*wv[i].y;
            acc.z += s*wv[i].z; acc.w += s*wv[i].w;
        }
        red[q][g][m] = acc;
    };
    do_mat(w1, 0);
    do_mat(w2, 1);
    do_mat(w3, 2);
    __syncthreads();

    if (t < 96) {
        const int q = t >> 5, mm = t & 31;
        float4 o = red[q][0][mm];
        #pragma unroll
        for (int gg = 1; gg < 8; ++gg) {
            const float4 r = red[q][gg][mm];
            o.x += r.x; o.y += r.y; o.z += r.z; o.w += r.w;
        }
        o.x = buntanh_f(o.x); o.y = buntanh_f(o.y);
        o.z = buntanh_f(o.z); o.w = buntanh_f(o.w);
        if (q == 0) {
            *(float4*)(dout + (size_t)node * OUT_STRIDE + ND + 4*mm) = o;   // prediction
        } else {
            float* base = (q == 1) ? Kg : Qg;                               // w2->K, w3->Q
            *(float4*)(base + ((size_t)node << 7) + 4*mm) = o;
        }
    }
}

// ---------- K2: raw_A = Q K^T * inv_sqrt_d -> M (bf16); ssq atomics ----------
__global__ __launch_bounds__(256) void qk2_kernel(
    const float* __restrict__ Qg, const float* __restrict__ Kg,
    unsigned* __restrict__ Mbf, float* __restrict__ reds)
{
    const int b = blockIdx.x >> 10;
    const int tile = blockIdx.x & 1023;
    const int tr = tile >> 5, tc = tile & 31;

    __shared__ float Qs[32][132];
    __shared__ float Ks[32][136];
    __shared__ float wr4[4];

    const int t = threadIdx.x;
    for (int i = t; i < 1024; i += 256) {
        const int r = i >> 5, q = i & 31;
        *(float4*)&Qs[r][q*4] = *(const float4*)(Qg + (((size_t)(b*NN + tr*32 + r)) << 7) + q*4);
        *(float4*)&Ks[r][q*4] = *(const float4*)(Kg + (((size_t)(b*NN + tc*32 + r)) << 7) + q*4);
    }
    __syncthreads();

    const int ty = t >> 4;        // rows ty, ty+16
    const int tx = t & 15;        // cols 2tx, 2tx+1
    float a00=0.f, a01=0.f, a10=0.f, a11=0.f;
    #pragma unroll
    for (int dq = 0; dq < 32; ++dq) {
        const float4 q0 = *(const float4*)&Qs[ty][dq*4];
        const float4 q1 = *(const float4*)&Qs[ty+16][dq*4];
        const float4 k0 = *(const float4*)&Ks[2*tx][dq*4];
        const float4 k1 = *(const float4*)&Ks[2*tx+1][dq*4];
        a00 += q0.x*k0.x + q0.y*k0.y + q0.z*k0.z + q0.w*k0.w;
        a01 += q0.x*k1.x + q0.y*k1.y + q0.z*k1.z + q0.w*k1.w;
        a10 += q1.x*k0.x + q1.y*k0.y + q1.z*k0.z + q1.w*k0.w;
        a11 += q1.x*k1.x + q1.y*k1.y + q1.z*k1.z + q1.w*k1.w;
    }
    a00 *= INV_SQRT_D; a01 *= INV_SQRT_D; a10 *= INV_SQRT_D; a11 *= INV_SQRT_D;

    unsigned* Mrow0 = Mbf + (((size_t)(b*NN + tr*32 + ty)) << 9) + tc*16;
    unsigned* Mrow1 = Mbf + (((size_t)(b*NN + tr*32 + ty + 16)) << 9) + tc*16;
    Mrow0[tx] = bf_pack(a00, a01);
    Mrow1[tx] = bf_pack(a10, a11);

    float ssq = a00*a00 + a01*a01 + a10*a10 + a11*a11;
    ssq = wave_sum(ssq);
    if ((t & 63) == 0) wr4[t >> 6] = ssq;
    __syncthreads();
    if (t == 0) atomicAdd(&reds[b], wr4[0]+wr4[1]+wr4[2]+wr4[3]);
}

// ---------- K3 x16: one Sinkhorn normalize pass over bf16 M ----------
// variant 0: EMA+mask+relu+eps then rowNorm (no pending colDiv)
// variant 1: colDiv + rowNorm ; variant 2: colDiv + threshold+eps + rowNorm
__global__ __launch_bounds__(1024) void sink_iter(
    unsigned* __restrict__ M, const float* __restrict__ A_ema,
    const float* __restrict__ reds, const float* __restrict__ csRd,
    float* __restrict__ csWr, float* __restrict__ csZr, int variant)
{
    __shared__ float invt[NN];
    __shared__ float colp[NN];
    const int t = threadIdx.x;
    const int b = blockIdx.x >> 6;
    const int pb = blockIdx.x & 63;

    colp[t] = 0.f;
    if (variant != 0) invt[t] = 1.f / csRd[b*NN + t];
    __syncthreads();

    const int w = t >> 6, l = t & 63;
    const int row = pb*16 + w;
    unsigned* Mrow = M + (((size_t)(b*NN + row)) << 9);
    uint4 u0 = ((const uint4*)Mrow)[l];
    uint4 u1 = ((const uint4*)Mrow)[l + 64];
    float v[16];
    v[0]=bflo(u0.x); v[1]=bfhi(u0.x); v[2]=bflo(u0.y); v[3]=bfhi(u0.y);
    v[4]=bflo(u0.z); v[5]=bfhi(u0.z); v[6]=bflo(u0.w); v[7]=bfhi(u0.w);
    v[8]=bflo(u1.x); v[9]=bfhi(u1.x); v[10]=bflo(u1.y); v[11]=bfhi(u1.y);
    v[12]=bflo(u1.z); v[13]=bfhi(u1.z); v[14]=bflo(u1.w); v[15]=bfhi(u1.w);

    if (variant == 0) {
        const float scale = rsqrtf(reds[b] * (1.0f/1048576.0f) + F_EPS);
        const float* erow = A_ema + (((size_t)(b*NN + row)) << 10);
        const float4 e0 = *(const float4*)&erow[8*l];
        const float4 e1 = *(const float4*)&erow[8*l + 4];
        const float4 e2 = *(const float4*)&erow[512 + 8*l];
        const float4 e3 = *(const float4*)&erow[512 + 8*l + 4];
        float ev[16] = {e0.x,e0.y,e0.z,e0.w, e1.x,e1.y,e1.z,e1.w,
                        e2.x,e2.y,e2.z,e2.w, e3.x,e3.y,e3.z,e3.w};
        #pragma unroll
        for (int j = 0; j < 16; ++j) {
            const int c = (j < 8) ? (8*l + j) : (512 + 8*l + (j-8));
            float em = ev[j];
            if (row == NUM_IN && c < NUM_IN) em += 3.0f / NUM_IN;
            float x = em * 0.99f + v[j] * scale * 0.01f;
            if (row < NUM_IN) x = 0.f;
            v[j] = fmaxf(x, 0.f) + F_EPS;
        }
    } else {
        #pragma unroll
        for (int j = 0; j < 16; ++j) {
            const int c = (j < 8) ? (8*l + j) : (512 + 8*l + (j-8));
            v[j] *= invt[c];
        }
        if (variant == 2) {
            #pragma unroll
            for (int j = 0; j < 16; ++j)
                v[j] = (v[j] > BASELINE ? v[j] : 0.f) + F_EPS;
        }
    }

    float s = 0.f;
    #pragma unroll
    for (int j = 0; j < 16; ++j) s += v[j];
    s = wave_sum(s);
    const float is = 1.f / s;
    #pragma unroll
    for (int j = 0; j < 16; ++j) v[j] *= is;

    u0.x = bf_pack(v[0],v[1]);  u0.y = bf_pack(v[2],v[3]);
    u0.z = bf_pack(v[4],v[5]);  u0.w = bf_pack(v[6],v[7]);
    u1.x = bf_pack(v[8],v[9]);  u1.y = bf_pack(v[10],v[11]);
    u1.z = bf_pack(v[12],v[13]); u1.w = bf_pack(v[14],v[15]);
    ((uint4*)Mrow)[l] = u0;
    ((uint4*)Mrow)[l + 64] = u1;

    #pragma unroll
    for (int j = 0; j < 8; ++j) atomicAdd(&colp[8*l + j], v[j]);
    #pragma unroll
    for (int j = 0; j < 8; ++j) atomicAdd(&colp[512 + 8*l + j], v[8 + j]);
    __syncthreads();

    atomicAdd(&csWr[b*NN + t], colp[t]);
    if (t < 16) csZr[(blockIdx.x << 4) + t] = 0.f;
}

// ---------- K4: final colDiv + row mask -> A (fp32, dout); variance partials ----------
__global__ __launch_bounds__(1024) void sink_fin(
    const unsigned* __restrict__ M, const float* __restrict__ csRd,
    float* __restrict__ reds, float* __restrict__ dout)
{
    __shared__ float invt[NN];
    __shared__ float wred[32];
    const int t = threadIdx.x;
    const int b = blockIdx.x >> 6;
    const int pb = blockIdx.x & 63;

    invt[t] = 1.f / csRd[b*NN + t];
    __syncthreads();

    const int w = t >> 6, l = t & 63;
    const int row = pb*16 + w;
    float* Arow = dout + A_OFF + (((size_t)(b*NN + row)) << 10);
    float s1 = 0.f, s2 = 0.f;

    if (pb < 4) {                       // rows < 64: masked to zero
        const float4 z = make_float4(0.f,0.f,0.f,0.f);
        ((float4*)Arow)[2*l] = z;       ((float4*)Arow)[2*l+1] = z;
        ((float4*)Arow)[128+2*l] = z;   ((float4*)Arow)[129+2*l] = z;
    } else {
        const unsigned* Mrow = M + (((size_t)(b*NN + row)) << 9);
        const uint4 u0 = ((const uint4*)Mrow)[l];
        const uint4 u1 = ((const uint4*)Mrow)[l + 64];
        float v[16];
        v[0]=bflo(u0.x); v[1]=bfhi(u0.x); v[2]=bflo(u0.y); v[3]=bfhi(u0.y);
        v[4]=bflo(u0.z); v[5]=bfhi(u0.z); v[6]=bflo(u0.w); v[7]=bfhi(u0.w);
        v[8]=bflo(u1.x); v[9]=bfhi(u1.x); v[10]=bflo(u1.y); v[11]=bfhi(u1.y);
        v[12]=bflo(u1.z); v[13]=bfhi(u1.z); v[14]=bflo(u1.w); v[15]=bfhi(u1.w);
        #pragma unroll
        for (int j = 0; j < 16; ++j) {
            const int c = (j < 8) ? (8*l + j) : (512 + 8*l + (j-8));
            v[j] *= invt[c];
            s1 += v[j]; s2 += v[j]*v[j];
        }
        ((float4*)Arow)[2*l]     = make_float4(v[0],v[1],v[2],v[3]);
        ((float4*)Arow)[2*l+1]   = make_float4(v[4],v[5],v[6],v[7]);
        ((float4*)Arow)[128+2*l] = make_float4(v[8],v[9],v[10],v[11]);
        ((float4*)Arow)[129+2*l] = make_float4(v[12],v[13],v[14],v[15]);
    }

    s1 = wave_sum(s1); s2 = wave_sum(s2);
    if (l == 0) { wred[w] = s1; wred[16 + w] = s2; }
    __syncthreads();
    if (t == 0) {
        float a = 0.f, c = 0.f;
        #pragma unroll
        for (int i = 0; i < 16; ++i) { a += wred[i]; c += wred[16+i]; }
        atomicAdd(&reds[4 + b], a);
        atomicAdd(&reds[8 + b], c);
    }
}

// ---------- K5: V = output + relu(0.02 - var) * noise ----------
__global__ __launch_bounds__(256) void vbuild_kernel(
    const float* __restrict__ outp, const float* __restrict__ noise,
    const float* __restrict__ reds, float* __restrict__ V)
{
    const int i = blockIdx.x * 256 + threadIdx.x;   // float4 idx, 131072 total
    const int b = i >> 15;
    const float Mn = 1048576.f;
    const float S1 = reds[4 + b], S2 = reds[8 + b];
    const float var = (S2 - S1*S1/Mn) / (Mn - 1.f);
    const float vd = fmaxf(0.02f - var, 0.f);
    const float4 o = ((const float4*)outp)[i];
    const float4 n = ((const float4*)noise)[i];
    ((float4*)V)[i] = make_float4(o.x + vd*n.x, o.y + vd*n.y,
                                  o.z + vd*n.z, o.w + vd*n.w);
}

// ---------- K6: target = softsign(A @ V); env rows overwrite ----------
__global__ __launch_bounds__(256) void av_kernel(
    const float* __restrict__ A,       // dout + A_OFF
    const float* __restrict__ V,
    const float* __restrict__ env,
    float* __restrict__ dout)
{
    const int b = blockIdx.x >> 5;
    const int rb = blockIdx.x & 31;
    const int r0 = rb << 5;
    const int t = threadIdx.x;

    if (r0 < NUM_IN) {                  // rows 0..63 -> env
        for (int i = t; i < 32 * ND; i += 256) {
            const int r = i >> 7, d = i & 127;
            dout[((size_t)(b*NN + r0 + r)) * OUT_STRIDE + d] =
                env[(size_t)b * 8192 + (size_t)(r0 + r) * ND + d];
        }
        return;
    }

    __shared__ float As[32][64];
    const int d = t & 127, rg = t >> 7;
    float acc[16];
    #pragma unroll
    for (int k = 0; k < 16; ++k) acc[k] = 0.f;
    const float* Vb = V + (size_t)b * (NN * ND) + d;

    for (int mc = 0; mc < 16; ++mc) {
        #pragma unroll
        for (int j = 0; j < 2; ++j) {
            const int f = 2*t + j, r = f >> 4, c4 = f & 15;
            *(float4*)&As[r][c4*4] =
                *(const float4*)(A + (((size_t)(b*NN + r0 + r)) << 10) + mc*64 + c4*4);
        }
        __syncthreads();
        #pragma unroll 4
        for (int mm4 = 0; mm4 < 16; ++mm4) {
            const float vv0 = Vb[(size_t)(mc*64 + mm4*4 + 0) * ND];
            const float vv1 = Vb[(size_t)(mc*64 + mm4*4 + 1) * ND];
            const float vv2 = Vb[(size_t)(mc*64 + mm4*4 + 2) * ND];
            const float vv3 = Vb[(size_t)(mc*64 + mm4*4 + 3) * ND];
            #pragma unroll
            for (int k = 0; k < 16; ++k) {
                const float4 a = *(const float4*)&As[rg*16 + k][mm4*4];
                acc[k] += a.x*vv0 + a.y*vv1 + a.z*vv2 + a.w*vv3;
            }
        }
        __syncthreads();
    }
    #pragma unroll
    for (int k = 0; k < 16; ++k) {
        const float o = acc[k];
        dout[((size_t)(b*NN + r0 + rg*16 + k)) * OUT_STRIDE + d] = o / (1.f + fabsf(o));
    }
}

extern "C" void kernel_launch(void* const* d_in, const int* in_sizes, int n_in,
                              void* d_out, int out_size, void* d_ws, size_t ws_size,
                              hipStream_t stream)
{
    (void)in_sizes; (void)n_in; (void)out_size; (void)ws_size;
    const float* state = (const float*)d_in[0];
    const float* outp  = (const float*)d_in[1];
    const float* w1    = (const float*)d_in[2];
    const float* w2    = (const float*)d_in[3];
    const float* w3    = (const float*)d_in[4];
    const float* A_ema = (const float*)d_in[5];
    const float* env   = (const float*)d_in[6];
    const float* noise = (const float*)d_in[7];
    float* dout = (float*)d_out;

    // ws layout (float units): Q | K | V | M(bf16, 2M uints) | csum[3][4096] | reds[16]
    float*    Qg   = (float*)d_ws;
    float*    Kg   = Qg + NB*NN*ND;
    float*    Vg   = Kg + NB*NN*ND;
    unsigned* Mbf  = (unsigned*)(Vg + NB*NN*ND);
    float*    csum = (float*)(Mbf + (size_t)NB*NN*NN/2);
    float*    reds = csum + 3*4096;

    hipMemsetAsync(csum, 0, 4096 * sizeof(float), stream);   // buf0 for pass 0
    hipMemsetAsync(reds, 0, 12 * sizeof(float), stream);

    qkp_kernel<<<dim3(NB*NN), dim3(256), 0, stream>>>(
        state, w1, w2, w3, dout, Qg, Kg);

    qk2_kernel<<<dim3(NB*1024), dim3(256), 0, stream>>>(Qg, Kg, Mbf, reds);

    for (int k = 0; k < 16; ++k) {
        const int variant = (k == 0) ? 0 : ((k == 8) ? 2 : 1);
        float* csRd = csum + ((k + 2) % 3) * 4096;
        float* csWr = csum + (k % 3) * 4096;
        float* csZr = csum + ((k + 1) % 3) * 4096;
        sink_iter<<<dim3(NB*64), dim3(1024), 0, stream>>>(
            Mbf, A_ema, reds, csRd, csWr, csZr, variant);
    }

    sink_fin<<<dim3(NB*64), dim3(1024), 0, stream>>>(Mbf, csum + 0, reds, dout);

    vbuild_kernel<<<dim3(512), dim3(256), 0, stream>>>(outp, noise, reds, Vg);

    av_kernel<<<dim3(NB*32), dim3(256), 0, stream>>>(dout + A_OFF, Vg, env, dout);
}

// Round 4
// 540.544 us; speedup vs baseline: 1.5196x; 1.5196x over previous
//
#include <hip/hip_runtime.h>
#include <math.h>

#define NB 4
#define NN 1024
#define ND 128
#define NUM_IN 64
#define F_EPS 1e-8f
#define BT_SCALE 1.8477590650225735f      // sqrt(2+sqrt(2))
#define INV_SQRT_D 0.08838834764831844f   // 1/sqrt(128)
#define BASELINE (1.0f/1025.0f)
#define OUT_STRIDE 256
#define A_OFF 1048576                     // floats: NB*NN*OUT_STRIDE

// swizzled LDS index for a 1024-vector accessed as v[8*lane + j]
#define SWZ(c) ((((c) & 7) << 7) | ((c) >> 3))

__device__ __forceinline__ float buntanh_f(float x) {
    return BT_SCALE * (0.5f * x + 0.5f * tanhf(x));
}
__device__ __forceinline__ float wave_sum(float v) {
    #pragma unroll
    for (int off = 32; off > 0; off >>= 1) v += __shfl_xor(v, off, 64);
    return v;
}
__device__ __forceinline__ float bflo(unsigned u) { return __uint_as_float(u << 16); }
__device__ __forceinline__ float bfhi(unsigned u) { return __uint_as_float(u & 0xffff0000u); }
__device__ __forceinline__ unsigned bf_rne(float f) {
    unsigned x = __float_as_uint(f);
    return (x + 0x7fffu + ((x >> 16) & 1u)) >> 16;
}
__device__ __forceinline__ unsigned bf_pack(float lo, float hi) {
    return bf_rne(lo) | (bf_rne(hi) << 16);
}

// ---------- K1: per-node matvecs (w1,w2,w3 fused) -> prediction, K, Q ----------
__global__ __launch_bounds__(256, 6) void qkp_kernel(
    const float* __restrict__ state,
    const float* __restrict__ w1,
    const float* __restrict__ w2,
    const float* __restrict__ w3,
    float* __restrict__ dout,
    float* __restrict__ Qg,
    float* __restrict__ Kg)
{
    // XCD-chunked swizzle: 4096 blocks, 8 XCDs -> contiguous 512-node chunks
    const int blk = blockIdx.x;
    const int node = ((blk & 7) << 9) | (blk >> 3);

    __shared__ float s_state[ND];
    __shared__ float4 red[3][8][32];

    const int t = threadIdx.x;
    if (t < 32) ((float4*)s_state)[t] =
        ((const float4*)(state + ((size_t)node << 7)))[t];
    __syncthreads();

    const int g = t >> 5, m = t & 31;

    auto do_mat = [&](const float* wbase, int q) {
        const float4* w4 = (const float4*)(wbase + ((size_t)node << 14));
        float4 wv[8];
        float4 acc = make_float4(0.f, 0.f, 0.f, 0.f);
        #pragma unroll
        for (int i = 0; i < 8; ++i) wv[i] = w4[i*256 + t];
        #pragma unroll
        for (int i = 0; i < 8; ++i) {
            const float s = s_state[i*8 + g];
            acc.x += s*wv[i].x; acc.y += s*wv[i].y;
            acc.z += s*wv[i].z; acc.w += s*wv[i].w;
        }
        #pragma unroll
        for (int i = 0; i < 8; ++i) wv[i] = w4[(8+i)*256 + t];
        #pragma unroll
        for (int i = 0; i < 8; ++i) {
            const float s = s_state[(8+i)*8 + g];
            acc.x += s*wv[i].x; acc.y += s*wv[i].y;
            acc.z += s*wv[i].z; acc.w += s*wv[i].w;
        }
        red[q][g][m] = acc;
    };
    do_mat(w1, 0);
    do_mat(w2, 1);
    do_mat(w3, 2);
    __syncthreads();

    if (t < 96) {
        const int q = t >> 5, mm = t & 31;
        float4 o = red[q][0][mm];
        #pragma unroll
        for (int gg = 1; gg < 8; ++gg) {
            const float4 r = red[q][gg][mm];
            o.x += r.x; o.y += r.y; o.z += r.z; o.w += r.w;
        }
        o.x = buntanh_f(o.x); o.y = buntanh_f(o.y);
        o.z = buntanh_f(o.z); o.w = buntanh_f(o.w);
        if (q == 0) {
            *(float4*)(dout + (size_t)node * OUT_STRIDE + ND + 4*mm) = o;   // prediction
        } else {
            float* base = (q == 1) ? Kg : Qg;                               // w2->K, w3->Q
            *(float4*)(base + ((size_t)node << 7) + 4*mm) = o;
        }
    }
}

// ---------- K2: raw_A = Q K^T * inv_sqrt_d -> raw (bf16); ssq atomics ----------
__global__ __launch_bounds__(256) void qk2_kernel(
    const float* __restrict__ Qg, const float* __restrict__ Kg,
    unsigned* __restrict__ rawbf, float* __restrict__ reds)
{
    const int b = blockIdx.x >> 10;
    const int tile = blockIdx.x & 1023;
    const int tr = tile >> 5, tc = tile & 31;

    __shared__ float Qs[32][132];
    __shared__ float Ks[32][136];
    __shared__ float wr4[4];

    const int t = threadIdx.x;
    for (int i = t; i < 1024; i += 256) {
        const int r = i >> 5, q = i & 31;
        *(float4*)&Qs[r][q*4] = *(const float4*)(Qg + (((size_t)(b*NN + tr*32 + r)) << 7) + q*4);
        *(float4*)&Ks[r][q*4] = *(const float4*)(Kg + (((size_t)(b*NN + tc*32 + r)) << 7) + q*4);
    }
    __syncthreads();

    const int ty = t >> 4;        // rows ty, ty+16
    const int tx = t & 15;        // cols 2tx, 2tx+1
    float a00=0.f, a01=0.f, a10=0.f, a11=0.f;
    #pragma unroll
    for (int dq = 0; dq < 32; ++dq) {
        const float4 q0 = *(const float4*)&Qs[ty][dq*4];
        const float4 q1 = *(const float4*)&Qs[ty+16][dq*4];
        const float4 k0 = *(const float4*)&Ks[2*tx][dq*4];
        const float4 k1 = *(const float4*)&Ks[2*tx+1][dq*4];
        a00 += q0.x*k0.x + q0.y*k0.y + q0.z*k0.z + q0.w*k0.w;
        a01 += q0.x*k1.x + q0.y*k1.y + q0.z*k1.z + q0.w*k1.w;
        a10 += q1.x*k0.x + q1.y*k0.y + q1.z*k0.z + q1.w*k0.w;
        a11 += q1.x*k1.x + q1.y*k1.y + q1.z*k1.z + q1.w*k1.w;
    }
    a00 *= INV_SQRT_D; a01 *= INV_SQRT_D; a10 *= INV_SQRT_D; a11 *= INV_SQRT_D;

    unsigned* r0p = rawbf + (((size_t)(b*NN + tr*32 + ty)) << 9) + tc*16;
    unsigned* r1p = rawbf + (((size_t)(b*NN + tr*32 + ty + 16)) << 9) + tc*16;
    r0p[tx] = bf_pack(a00, a01);
    r1p[tx] = bf_pack(a10, a11);

    float ssq = a00*a00 + a01*a01 + a10*a10 + a11*a11;
    ssq = wave_sum(ssq);
    if ((t & 63) == 0) wr4[t >> 6] = ssq;
    __syncthreads();
    if (t == 0) atomicAdd(&reds[b], wr4[0]+wr4[1]+wr4[2]+wr4[3]);
}

// ---------- K3: EMA+mask+eps transform; write M0, M0^T (bf16); rowsum atomics ----------
// grid: 4 batches x 256 tiles (64x64); 256 threads
__global__ __launch_bounds__(256) void emaT_kernel(
    const unsigned* __restrict__ rawbf, const float* __restrict__ A_ema,
    const float* __restrict__ reds,
    unsigned* __restrict__ M0, unsigned* __restrict__ M0T,
    float* __restrict__ SR)
{
    const int b = blockIdx.x >> 8;
    const int tile = blockIdx.x & 255;
    const int tr = tile >> 4, tc = tile & 15;
    const int R0 = tr << 6, C0 = tc << 6;

    __shared__ float st[64][65];
    __shared__ float s_part[64][5];

    const int t = threadIdx.x;
    const int r = t >> 2, q = t & 3;
    const int row = R0 + r;
    const float scale = rsqrtf(reds[b] * (1.0f/1048576.0f) + F_EPS);

    const unsigned* rawrow = rawbf + (((size_t)(b*NN + row)) << 9) + tc*8*4;
    const uint4 u0 = ((const uint4*)rawrow)[q*2];
    const uint4 u1 = ((const uint4*)rawrow)[q*2 + 1];
    float rv[16];
    rv[0]=bflo(u0.x); rv[1]=bfhi(u0.x); rv[2]=bflo(u0.y); rv[3]=bfhi(u0.y);
    rv[4]=bflo(u0.z); rv[5]=bfhi(u0.z); rv[6]=bflo(u0.w); rv[7]=bfhi(u0.w);
    rv[8]=bflo(u1.x); rv[9]=bfhi(u1.x); rv[10]=bflo(u1.y); rv[11]=bfhi(u1.y);
    rv[12]=bflo(u1.z); rv[13]=bfhi(u1.z); rv[14]=bflo(u1.w); rv[15]=bfhi(u1.w);

    const float* emarow = A_ema + (((size_t)(b*NN + row)) << 10) + C0 + q*16;
    float s = 0.f;
    #pragma unroll
    for (int j = 0; j < 4; ++j) {
        const float4 e = ((const float4*)emarow)[j];
        float ev[4] = {e.x, e.y, e.z, e.w};
        #pragma unroll
        for (int k = 0; k < 4; ++k) {
            const int e_idx = j*4 + k;
            const int c = C0 + q*16 + e_idx;
            float em = ev[k];
            if (row == NUM_IN && c < NUM_IN) em += 3.0f / NUM_IN;
            float v = em * 0.99f + rv[e_idx] * scale * 0.01f;
            if (row < NUM_IN) v = 0.f;
            v = fmaxf(v, 0.f) + F_EPS;
            rv[e_idx] = v;
            st[r][q*16 + e_idx] = v;
            s += v;
        }
    }
    s_part[r][q] = s;

    // write M0 (row-major, same layout as raw)
    unsigned* m0row = M0 + (((size_t)(b*NN + row)) << 9) + tc*8*4;
    uint4 o0, o1;
    o0.x = bf_pack(rv[0],rv[1]);  o0.y = bf_pack(rv[2],rv[3]);
    o0.z = bf_pack(rv[4],rv[5]);  o0.w = bf_pack(rv[6],rv[7]);
    o1.x = bf_pack(rv[8],rv[9]);  o1.y = bf_pack(rv[10],rv[11]);
    o1.z = bf_pack(rv[12],rv[13]); o1.w = bf_pack(rv[14],rv[15]);
    ((uint4*)m0row)[q*2]     = o0;
    ((uint4*)m0row)[q*2 + 1] = o1;
    __syncthreads();

    // rowsum atomics
    if (t < 64) {
        const float rs = s_part[t][0] + s_part[t][1] + s_part[t][2] + s_part[t][3];
        atomicAdd(&SR[b*NN + R0 + t], rs);
    }

    // write M0^T tile: T-row = global col C0+cT; elements over r
    const int cT = t >> 2;
    float tv[16];
    #pragma unroll
    for (int k = 0; k < 16; ++k) tv[k] = st[q*16 + k][cT];
    uint4 w0, w1;
    w0.x = bf_pack(tv[0],tv[1]);  w0.y = bf_pack(tv[2],tv[3]);
    w0.z = bf_pack(tv[4],tv[5]);  w0.w = bf_pack(tv[6],tv[7]);
    w1.x = bf_pack(tv[8],tv[9]);  w1.y = bf_pack(tv[10],tv[11]);
    w1.z = bf_pack(tv[12],tv[13]); w1.w = bf_pack(tv[14],tv[15]);
    unsigned* mtrow = M0T + (((size_t)(b*NN + C0 + cT)) << 9) + tr*8*4;
    ((uint4*)mtrow)[q*2]     = w0;
    ((uint4*)mtrow)[q*2 + 1] = w1;
}

// ---------- K4 x30: y = A . (1/x)   (sum-form Sinkhorn scaling update) ----------
// grid 1024 blocks x 64 threads; block = 4 rows of A (bf16, row-major 512 uints)
__global__ __launch_bounds__(64) void mv_kernel(
    const unsigned* __restrict__ Abf, const float* __restrict__ x,
    float* __restrict__ y)
{
    __shared__ float xs[NN];
    const int blk = blockIdx.x;
    const int lp = ((blk & 7) << 7) | (blk >> 3);    // XCD-chunked
    const int b = lp >> 8;
    const int r0 = (lp & 255) << 2;
    const int t = threadIdx.x;

    #pragma unroll
    for (int i = 0; i < 16; ++i) {
        const int c = t + i*64;
        xs[SWZ(c)] = 1.0f / x[b*NN + c];
    }
    __syncthreads();

    const unsigned* base = Abf + (((size_t)(b*NN + r0)) << 9);
    uint4 u[4][2];
    #pragma unroll
    for (int r = 0; r < 4; ++r) {
        const uint4* rp = (const uint4*)(base + (size_t)r * 512);
        u[r][0] = rp[t];
        u[r][1] = rp[64 + t];
    }
    #pragma unroll
    for (int r = 0; r < 4; ++r) {
        float a = 0.f;
        const uint4 v0 = u[r][0], v1 = u[r][1];
        a += bflo(v0.x)*xs[0*128+t] + bfhi(v0.x)*xs[1*128+t];
        a += bflo(v0.y)*xs[2*128+t] + bfhi(v0.y)*xs[3*128+t];
        a += bflo(v0.z)*xs[4*128+t] + bfhi(v0.z)*xs[5*128+t];
        a += bflo(v0.w)*xs[6*128+t] + bfhi(v0.w)*xs[7*128+t];
        a += bflo(v1.x)*xs[0*128+64+t] + bfhi(v1.x)*xs[1*128+64+t];
        a += bflo(v1.y)*xs[2*128+64+t] + bfhi(v1.y)*xs[3*128+64+t];
        a += bflo(v1.z)*xs[4*128+64+t] + bfhi(v1.z)*xs[5*128+64+t];
        a += bflo(v1.w)*xs[6*128+64+t] + bfhi(v1.w)*xs[7*128+64+t];
        a = wave_sum(a);
        if (t == 0) y[b*NN + r0 + r] = a;
    }
}

// ---------- K5: threshold+eps -> A1, A1^T (bf16); rowsums of A1 -> SR2 ----------
// grid 256 blocks x 256 thr; waves 0,1: 16 A1 rows; waves 2,3: 16 A1T rows
__global__ __launch_bounds__(256) void thresh_kernel(
    const unsigned* __restrict__ M0, const unsigned* __restrict__ M0T,
    const float* __restrict__ SR, const float* __restrict__ SC,
    unsigned* __restrict__ A1, unsigned* __restrict__ A1T,
    float* __restrict__ SR2)
{
    __shared__ float invRs[NN];
    __shared__ float invCs[NN];
    const int t = threadIdx.x;
    const int b = blockIdx.x >> 6;
    const int g0 = (blockIdx.x & 63) << 4;

    #pragma unroll
    for (int i = 0; i < 4; ++i) {
        const int c = t + i*256;
        invRs[SWZ(c)] = 1.0f / SR[b*NN + c];
        invCs[SWZ(c)] = 1.0f / SC[b*NN + c];
    }
    __syncthreads();

    const int w = t >> 6, l = t & 63;
    const bool doA1 = (w < 2);
    const int wr = doA1 ? w : (w - 2);
    const unsigned* src = doA1 ? M0 : M0T;
    unsigned*       dst = doA1 ? A1 : A1T;
    const float* rowScale = doA1 ? invRs : invCs;
    const float* colScale = doA1 ? invCs : invRs;

    for (int rr = 0; rr < 8; ++rr) {
        const int row = g0 + wr*8 + rr;
        const float ri = rowScale[SWZ(row)];
        const unsigned* rp = src + (((size_t)(b*NN + row)) << 9);
        const uint4 v0 = ((const uint4*)rp)[l];
        const uint4 v1 = ((const uint4*)rp)[64 + l];
        float e[16];
        e[0]=bflo(v0.x); e[1]=bfhi(v0.x); e[2]=bflo(v0.y); e[3]=bfhi(v0.y);
        e[4]=bflo(v0.z); e[5]=bfhi(v0.z); e[6]=bflo(v0.w); e[7]=bfhi(v0.w);
        e[8]=bflo(v1.x); e[9]=bfhi(v1.x); e[10]=bflo(v1.y); e[11]=bfhi(v1.y);
        e[12]=bflo(v1.z); e[13]=bfhi(v1.z); e[14]=bflo(v1.w); e[15]=bfhi(v1.w);
        float s = 0.f;
        #pragma unroll
        for (int j = 0; j < 8; ++j) {
            float d = e[j] * ri * colScale[j*128 + l];
            e[j] = (d > BASELINE ? d : 0.f) + F_EPS;
            s += e[j];
        }
        #pragma unroll
        for (int j = 0; j < 8; ++j) {
            float d = e[8+j] * ri * colScale[j*128 + 64 + l];
            e[8+j] = (d > BASELINE ? d : 0.f) + F_EPS;
            s += e[8+j];
        }
        uint4 o0, o1;
        o0.x = bf_pack(e[0],e[1]);  o0.y = bf_pack(e[2],e[3]);
        o0.z = bf_pack(e[4],e[5]);  o0.w = bf_pack(e[6],e[7]);
        o1.x = bf_pack(e[8],e[9]);  o1.y = bf_pack(e[10],e[11]);
        o1.z = bf_pack(e[12],e[13]); o1.w = bf_pack(e[14],e[15]);
        unsigned* op = dst + (((size_t)(b*NN + row)) << 9);
        ((uint4*)op)[l] = o0;
        ((uint4*)op)[64 + l] = o1;
        if (doA1) {
            s = wave_sum(s);
            if (l == 0) SR2[b*NN + row] = s;
        }
    }
}

// ---------- K6: final scale + mask -> A (fp32, dout); variance partials ----------
__global__ __launch_bounds__(256) void fin_kernel(
    const unsigned* __restrict__ A1, const float* __restrict__ SR,
    const float* __restrict__ SC, float* __restrict__ reds,
    float* __restrict__ dout)
{
    __shared__ float invRs[NN];
    __shared__ float invCs[NN];
    __shared__ float wred[8];
    const int t = threadIdx.x;
    const int b = blockIdx.x >> 6;
    const int g0 = (blockIdx.x & 63) << 4;

    #pragma unroll
    for (int i = 0; i < 4; ++i) {
        const int c = t + i*256;
        invRs[SWZ(c)] = 1.0f / SR[b*NN + c];
        invCs[SWZ(c)] = 1.0f / SC[b*NN + c];
    }
    __syncthreads();

    const int w = t >> 6, l = t & 63;
    float s1 = 0.f, s2 = 0.f;
    for (int rr = 0; rr < 4; ++rr) {
        const int row = g0 + w*4 + rr;
        float* Arow = dout + A_OFF + (((size_t)(b*NN + row)) << 10);
        if (row < NUM_IN) {
            const float4 z = make_float4(0.f,0.f,0.f,0.f);
            ((float4*)Arow)[2*l] = z;       ((float4*)Arow)[2*l+1] = z;
            ((float4*)Arow)[128+2*l] = z;   ((float4*)Arow)[129+2*l] = z;
        } else {
            const float ri = invRs[SWZ(row)];
            const unsigned* rp = A1 + (((size_t)(b*NN + row)) << 9);
            const uint4 v0 = ((const uint4*)rp)[l];
            const uint4 v1 = ((const uint4*)rp)[64 + l];
            float e[16];
            e[0]=bflo(v0.x); e[1]=bfhi(v0.x); e[2]=bflo(v0.y); e[3]=bfhi(v0.y);
            e[4]=bflo(v0.z); e[5]=bfhi(v0.z); e[6]=bflo(v0.w); e[7]=bfhi(v0.w);
            e[8]=bflo(v1.x); e[9]=bfhi(v1.x); e[10]=bflo(v1.y); e[11]=bfhi(v1.y);
            e[12]=bflo(v1.z); e[13]=bfhi(v1.z); e[14]=bflo(v1.w); e[15]=bfhi(v1.w);
            #pragma unroll
            for (int j = 0; j < 8; ++j) {
                e[j] = e[j] * ri * invCs[j*128 + l];
                s1 += e[j]; s2 += e[j]*e[j];
            }
            #pragma unroll
            for (int j = 0; j < 8; ++j) {
                e[8+j] = e[8+j] * ri * invCs[j*128 + 64 + l];
                s1 += e[8+j]; s2 += e[8+j]*e[8+j];
            }
            ((float4*)Arow)[2*l]     = make_float4(e[0],e[1],e[2],e[3]);
            ((float4*)Arow)[2*l+1]   = make_float4(e[4],e[5],e[6],e[7]);
            ((float4*)Arow)[128+2*l] = make_float4(e[8],e[9],e[10],e[11]);
            ((float4*)Arow)[129+2*l] = make_float4(e[12],e[13],e[14],e[15]);
        }
    }
    s1 = wave_sum(s1); s2 = wave_sum(s2);
    if (l == 0) { wred[w] = s1; wred[4 + w] = s2; }
    __syncthreads();
    if (t == 0) {
        atomicAdd(&reds[4 + b], wred[0]+wred[1]+wred[2]+wred[3]);
        atomicAdd(&reds[8 + b], wred[4]+wred[5]+wred[6]+wred[7]);
    }
}

// ---------- K7: V = output + relu(0.02 - var) * noise ----------
__global__ __launch_bounds__(256) void vbuild_kernel(
    const float* __restrict__ outp, const float* __restrict__ noise,
    const float* __restrict__ reds, float* __restrict__ V)
{
    const int i = blockIdx.x * 256 + threadIdx.x;   // float4 idx, 131072 total
    const int b = i >> 15;
    const float Mn = 1048576.f;
    const float S1 = reds[4 + b], S2 = reds[8 + b];
    const float var = (S2 - S1*S1/Mn) / (Mn - 1.f);
    const float vd = fmaxf(0.02f - var, 0.f);
    const float4 o = ((const float4*)outp)[i];
    const float4 n = ((const float4*)noise)[i];
    ((float4*)V)[i] = make_float4(o.x + vd*n.x, o.y + vd*n.y,
                                  o.z + vd*n.z, o.w + vd*n.w);
}

// ---------- K8: target = softsign(A @ V); env rows overwrite ----------
__global__ __launch_bounds__(256) void av_kernel(
    const float* __restrict__ A,       // dout + A_OFF (fp32)
    const float* __restrict__ V,
    const float* __restrict__ env,
    float* __restrict__ dout)
{
    const int b = blockIdx.x >> 5;
    const int rb = blockIdx.x & 31;
    const int r0 = rb << 5;
    const int t = threadIdx.x;

    if (r0 < NUM_IN) {                  // rows 0..63 -> env
        for (int i = t; i < 32 * ND; i += 256) {
            const int r = i >> 7, d = i & 127;
            dout[((size_t)(b*NN + r0 + r)) * OUT_STRIDE + d] =
                env[(size_t)b * 8192 + (size_t)(r0 + r) * ND + d];
        }
        return;
    }

    __shared__ float As[32][64];
    const int d = t & 127, rg = t >> 7;
    float acc[16];
    #pragma unroll
    for (int k = 0; k < 16; ++k) acc[k] = 0.f;
    const float* Vb = V + (size_t)b * (NN * ND) + d;

    for (int mc = 0; mc < 16; ++mc) {
        #pragma unroll
        for (int j = 0; j < 2; ++j) {
            const int f = 2*t + j, r = f >> 4, c4 = f & 15;
            *(float4*)&As[r][c4*4] =
                *(const float4*)(A + (((size_t)(b*NN + r0 + r)) << 10) + mc*64 + c4*4);
        }
        __syncthreads();
        #pragma unroll 4
        for (int mm4 = 0; mm4 < 16; ++mm4) {
            const float vv0 = Vb[(size_t)(mc*64 + mm4*4 + 0) * ND];
            const float vv1 = Vb[(size_t)(mc*64 + mm4*4 + 1) * ND];
            const float vv2 = Vb[(size_t)(mc*64 + mm4*4 + 2) * ND];
            const float vv3 = Vb[(size_t)(mc*64 + mm4*4 + 3) * ND];
            #pragma unroll
            for (int k = 0; k < 16; ++k) {
                const float4 a = *(const float4*)&As[rg*16 + k][mm4*4];
                acc[k] += a.x*vv0 + a.y*vv1 + a.z*vv2 + a.w*vv3;
            }
        }
        __syncthreads();
    }
    #pragma unroll
    for (int k = 0; k < 16; ++k) {
        const float o = acc[k];
        dout[((size_t)(b*NN + r0 + rg*16 + k)) * OUT_STRIDE + d] = o / (1.f + fabsf(o));
    }
}

extern "C" void kernel_launch(void* const* d_in, const int* in_sizes, int n_in,
                              void* d_out, int out_size, void* d_ws, size_t ws_size,
                              hipStream_t stream)
{
    (void)in_sizes; (void)n_in; (void)out_size; (void)ws_size;
    const float* state = (const float*)d_in[0];
    const float* outp  = (const float*)d_in[1];
    const float* w1    = (const float*)d_in[2];
    const float* w2    = (const float*)d_in[3];
    const float* w3    = (const float*)d_in[4];
    const float* A_ema = (const float*)d_in[5];
    const float* env   = (const float*)d_in[6];
    const float* noise = (const float*)d_in[7];
    float* dout = (float*)d_out;

    // M0 / M0^T live in dout's A-region (dead until fin overwrites it with A)
    unsigned* M0  = (unsigned*)(dout + A_OFF);
    unsigned* M0T = M0 + 2097152;

    // ws layout (floats): Q(512K) K(512K) V(512K) | raw/A1 (2M) | A1T (2M) | vecs
    float*    Qg   = (float*)d_ws;
    float*    Kg   = Qg + 524288;
    float*    Vg   = Kg + 524288;
    unsigned* raw  = (unsigned*)(Vg + 524288);   // reused as A1 after emaT
    unsigned* A1   = raw;
    unsigned* A1T  = raw + 2097152;
    float*    SR1  = (float*)(A1T + 2097152);
    float*    SC1  = SR1 + NN;  // per-batch stride handled by b*NN (4 batches -> 4096)
    // NOTE: vectors are [4][1024]:
    // SR1: +0 .. 4095, SC1: +4096.., SR2: +8192.., SC2: +12288.., reds: +16384
    float*    SC1v = SR1 + 4096;
    float*    SR2  = SR1 + 8192;
    float*    SC2  = SR1 + 12288;
    float*    reds = SR1 + 16384;
    (void)SC1;

    hipMemsetAsync(SR1, 0, (16384 + 16) * sizeof(float), stream);

    qkp_kernel<<<dim3(NB*NN), dim3(256), 0, stream>>>(
        state, w1, w2, w3, dout, Qg, Kg);

    qk2_kernel<<<dim3(NB*1024), dim3(256), 0, stream>>>(Qg, Kg, raw, reds);

    emaT_kernel<<<dim3(NB*256), dim3(256), 0, stream>>>(
        raw, A_ema, reds, M0, M0T, SR1);

    // Sinkhorn call 1: R1 (= SR1) from emaT; then C1,R2,...,R8,C8 = 15 matvecs
    for (int k = 0; k < 15; ++k) {
        if ((k & 1) == 0)
            mv_kernel<<<dim3(1024), dim3(64), 0, stream>>>(M0T, SR1, SC1v);
        else
            mv_kernel<<<dim3(1024), dim3(64), 0, stream>>>(M0, SC1v, SR1);
    }

    thresh_kernel<<<dim3(NB*64), dim3(256), 0, stream>>>(
        M0, M0T, SR1, SC1v, A1, A1T, SR2);

    // Sinkhorn call 2
    for (int k = 0; k < 15; ++k) {
        if ((k & 1) == 0)
            mv_kernel<<<dim3(1024), dim3(64), 0, stream>>>(A1T, SR2, SC2);
        else
            mv_kernel<<<dim3(1024), dim3(64), 0, stream>>>(A1, SC2, SR2);
    }

    fin_kernel<<<dim3(NB*64), dim3(256), 0, stream>>>(A1, SR2, SC2, reds, dout);

    vbuild_kernel<<<dim3(512), dim3(256), 0, stream>>>(outp, noise, reds, Vg);

    av_kernel<<<dim3(NB*32), dim3(256), 0, stream>>>(dout + A_OFF, Vg, env, dout);
}

// Round 5
// 503.039 us; speedup vs baseline: 1.6329x; 1.0746x over previous
//
#include <hip/hip_runtime.h>
#include <math.h>

#define NB 4
#define NN 1024
#define ND 128
#define NUM_IN 64
#define F_EPS 1e-8f
#define BT_SCALE 1.8477590650225735f      // sqrt(2+sqrt(2))
#define INV_SQRT_D 0.08838834764831844f   // 1/sqrt(128)
#define BASELINE (1.0f/1025.0f)
#define OUT_STRIDE 256
#define A_OFF 1048576                     // floats: NB*NN*OUT_STRIDE

__device__ __forceinline__ float buntanh_f(float x) {
    return BT_SCALE * (0.5f * x + 0.5f * tanhf(x));
}
__device__ __forceinline__ float wave_sum(float v) {
    #pragma unroll
    for (int off = 32; off > 0; off >>= 1) v += __shfl_xor(v, off, 64);
    return v;
}
__device__ __forceinline__ float bflo(unsigned u) { return __uint_as_float(u << 16); }
__device__ __forceinline__ float bfhi(unsigned u) { return __uint_as_float(u & 0xffff0000u); }
__device__ __forceinline__ unsigned bf_rne(float f) {
    unsigned x = __float_as_uint(f);
    return (x + 0x7fffu + ((x >> 16) & 1u)) >> 16;
}
__device__ __forceinline__ unsigned bf_pack(float lo, float hi) {
    return bf_rne(lo) | (bf_rne(hi) << 16);
}

typedef float f32x4 __attribute__((ext_vector_type(4)));
__device__ __forceinline__ float4 ntload4(const float4* p) {
    f32x4 v = __builtin_nontemporal_load((const f32x4*)p);
    return make_float4(v.x, v.y, v.z, v.w);
}

// ---------- K1: per-node matvecs (w1,w2,w3 fused) -> prediction, K, Q ----------
__global__ __launch_bounds__(256, 6) void qkp_kernel(
    const float* __restrict__ state,
    const float* __restrict__ w1,
    const float* __restrict__ w2,
    const float* __restrict__ w3,
    float* __restrict__ dout,
    float* __restrict__ Qg,
    float* __restrict__ Kg)
{
    const int blk = blockIdx.x;
    const int node = ((blk & 7) << 9) | (blk >> 3);   // XCD-chunked

    __shared__ float s_state[ND];
    __shared__ float4 red[3][8][32];

    const int t = threadIdx.x;
    if (t < 32) ((float4*)s_state)[t] =
        ((const float4*)(state + ((size_t)node << 7)))[t];
    __syncthreads();

    const int g = t >> 5, m = t & 31;

    auto do_mat = [&](const float* wbase, int q) {
        const float4* w4 = (const float4*)(wbase + ((size_t)node << 14));
        float4 wv[8];
        float4 acc = make_float4(0.f, 0.f, 0.f, 0.f);
        #pragma unroll
        for (int i = 0; i < 8; ++i) wv[i] = ntload4(&w4[i*256 + t]);
        #pragma unroll
        for (int i = 0; i < 8; ++i) {
            const float s = s_state[i*8 + g];
            acc.x += s*wv[i].x; acc.y += s*wv[i].y;
            acc.z += s*wv[i].z; acc.w += s*wv[i].w;
        }
        #pragma unroll
        for (int i = 0; i < 8; ++i) wv[i] = ntload4(&w4[(8+i)*256 + t]);
        #pragma unroll
        for (int i = 0; i < 8; ++i) {
            const float s = s_state[(8+i)*8 + g];
            acc.x += s*wv[i].x; acc.y += s*wv[i].y;
            acc.z += s*wv[i].z; acc.w += s*wv[i].w;
        }
        red[q][g][m] = acc;
    };
    do_mat(w1, 0);
    do_mat(w2, 1);
    do_mat(w3, 2);
    __syncthreads();

    if (t < 96) {
        const int q = t >> 5, mm = t & 31;
        float4 o = red[q][0][mm];
        #pragma unroll
        for (int gg = 1; gg < 8; ++gg) {
            const float4 r = red[q][gg][mm];
            o.x += r.x; o.y += r.y; o.z += r.z; o.w += r.w;
        }
        o.x = buntanh_f(o.x); o.y = buntanh_f(o.y);
        o.z = buntanh_f(o.z); o.w = buntanh_f(o.w);
        if (q == 0) {
            *(float4*)(dout + (size_t)node * OUT_STRIDE + ND + 4*mm) = o;   // prediction
        } else {
            float* base = (q == 1) ? Kg : Qg;                               // w2->K, w3->Q
            *(float4*)(base + ((size_t)node << 7) + 4*mm) = o;
        }
    }
}

// ---------- K2: raw_A = Q K^T * inv_sqrt_d -> raw (bf16); ssq atomics ----------
__global__ __launch_bounds__(256) void qk2_kernel(
    const float* __restrict__ Qg, const float* __restrict__ Kg,
    unsigned* __restrict__ rawbf, float* __restrict__ reds)
{
    const int b = blockIdx.x >> 10;
    const int tile = blockIdx.x & 1023;
    const int tr = tile >> 5, tc = tile & 31;

    __shared__ float Qs[32][132];
    __shared__ float Ks[32][136];
    __shared__ float wr4[4];

    const int t = threadIdx.x;
    for (int i = t; i < 1024; i += 256) {
        const int r = i >> 5, q = i & 31;
        *(float4*)&Qs[r][q*4] = *(const float4*)(Qg + (((size_t)(b*NN + tr*32 + r)) << 7) + q*4);
        *(float4*)&Ks[r][q*4] = *(const float4*)(Kg + (((size_t)(b*NN + tc*32 + r)) << 7) + q*4);
    }
    __syncthreads();

    const int ty = t >> 4;        // rows ty, ty+16
    const int tx = t & 15;        // cols 2tx, 2tx+1
    float a00=0.f, a01=0.f, a10=0.f, a11=0.f;
    #pragma unroll
    for (int dq = 0; dq < 32; ++dq) {
        const float4 q0 = *(const float4*)&Qs[ty][dq*4];
        const float4 q1 = *(const float4*)&Qs[ty+16][dq*4];
        const float4 k0 = *(const float4*)&Ks[2*tx][dq*4];
        const float4 k1 = *(const float4*)&Ks[2*tx+1][dq*4];
        a00 += q0.x*k0.x + q0.y*k0.y + q0.z*k0.z + q0.w*k0.w;
        a01 += q0.x*k1.x + q0.y*k1.y + q0.z*k1.z + q0.w*k1.w;
        a10 += q1.x*k0.x + q1.y*k0.y + q1.z*k0.z + q1.w*k0.w;
        a11 += q1.x*k1.x + q1.y*k1.y + q1.z*k1.z + q1.w*k1.w;
    }
    a00 *= INV_SQRT_D; a01 *= INV_SQRT_D; a10 *= INV_SQRT_D; a11 *= INV_SQRT_D;

    unsigned* r0p = rawbf + (((size_t)(b*NN + tr*32 + ty)) << 9) + tc*16;
    unsigned* r1p = rawbf + (((size_t)(b*NN + tr*32 + ty + 16)) << 9) + tc*16;
    r0p[tx] = bf_pack(a00, a01);
    r1p[tx] = bf_pack(a10, a11);

    float ssq = a00*a00 + a01*a01 + a10*a10 + a11*a11;
    ssq = wave_sum(ssq);
    if ((t & 63) == 0) wr4[t >> 6] = ssq;
    __syncthreads();
    if (t == 0) atomicAdd(&reds[b], wr4[0]+wr4[1]+wr4[2]+wr4[3]);
}

// ---------- K3: EMA+mask+eps transform; write M0, M0^T (bf16); rowsum atomics ----------
__global__ __launch_bounds__(256) void emaT_kernel(
    const unsigned* __restrict__ rawbf, const float* __restrict__ A_ema,
    const float* __restrict__ reds,
    unsigned* __restrict__ M0, unsigned* __restrict__ M0T,
    float* __restrict__ SR)
{
    const int b = blockIdx.x >> 8;
    const int tile = blockIdx.x & 255;
    const int tr = tile >> 4, tc = tile & 15;
    const int R0 = tr << 6, C0 = tc << 6;

    __shared__ float st[64][65];
    __shared__ float s_part[64][5];

    const int t = threadIdx.x;
    const int r = t >> 2, q = t & 3;
    const int row = R0 + r;
    const float scale = rsqrtf(reds[b] * (1.0f/1048576.0f) + F_EPS);

    const unsigned* rawrow = rawbf + (((size_t)(b*NN + row)) << 9) + tc*8*4;
    const uint4 u0 = ((const uint4*)rawrow)[q*2];
    const uint4 u1 = ((const uint4*)rawrow)[q*2 + 1];
    float rv[16];
    rv[0]=bflo(u0.x); rv[1]=bfhi(u0.x); rv[2]=bflo(u0.y); rv[3]=bfhi(u0.y);
    rv[4]=bflo(u0.z); rv[5]=bfhi(u0.z); rv[6]=bflo(u0.w); rv[7]=bfhi(u0.w);
    rv[8]=bflo(u1.x); rv[9]=bfhi(u1.x); rv[10]=bflo(u1.y); rv[11]=bfhi(u1.y);
    rv[12]=bflo(u1.z); rv[13]=bfhi(u1.z); rv[14]=bflo(u1.w); rv[15]=bfhi(u1.w);

    const float* emarow = A_ema + (((size_t)(b*NN + row)) << 10) + C0 + q*16;
    float s = 0.f;
    #pragma unroll
    for (int j = 0; j < 4; ++j) {
        const float4 e = ((const float4*)emarow)[j];
        float ev[4] = {e.x, e.y, e.z, e.w};
        #pragma unroll
        for (int k = 0; k < 4; ++k) {
            const int e_idx = j*4 + k;
            const int c = C0 + q*16 + e_idx;
            float em = ev[k];
            if (row == NUM_IN && c < NUM_IN) em += 3.0f / NUM_IN;
            float v = em * 0.99f + rv[e_idx] * scale * 0.01f;
            if (row < NUM_IN) v = 0.f;
            v = fmaxf(v, 0.f) + F_EPS;
            rv[e_idx] = v;
            st[r][q*16 + e_idx] = v;
            s += v;
        }
    }
    s_part[r][q] = s;

    unsigned* m0row = M0 + (((size_t)(b*NN + row)) << 9) + tc*8*4;
    uint4 o0, o1;
    o0.x = bf_pack(rv[0],rv[1]);  o0.y = bf_pack(rv[2],rv[3]);
    o0.z = bf_pack(rv[4],rv[5]);  o0.w = bf_pack(rv[6],rv[7]);
    o1.x = bf_pack(rv[8],rv[9]);  o1.y = bf_pack(rv[10],rv[11]);
    o1.z = bf_pack(rv[12],rv[13]); o1.w = bf_pack(rv[14],rv[15]);
    ((uint4*)m0row)[q*2]     = o0;
    ((uint4*)m0row)[q*2 + 1] = o1;
    __syncthreads();

    if (t < 64) {
        const float rs = s_part[t][0] + s_part[t][1] + s_part[t][2] + s_part[t][3];
        atomicAdd(&SR[b*NN + R0 + t], rs);
    }

    const int cT = t >> 2;
    float tv[16];
    #pragma unroll
    for (int k = 0; k < 16; ++k) tv[k] = st[q*16 + k][cT];
    uint4 w0, w1;
    w0.x = bf_pack(tv[0],tv[1]);  w0.y = bf_pack(tv[2],tv[3]);
    w0.z = bf_pack(tv[4],tv[5]);  w0.w = bf_pack(tv[6],tv[7]);
    w1.x = bf_pack(tv[8],tv[9]);  w1.y = bf_pack(tv[10],tv[11]);
    w1.z = bf_pack(tv[12],tv[13]); w1.w = bf_pack(tv[14],tv[15]);
    unsigned* mtrow = M0T + (((size_t)(b*NN + C0 + cT)) << 9) + tr*8*4;
    ((uint4*)mtrow)[q*2]     = w0;
    ((uint4*)mtrow)[q*2 + 1] = w1;
}

// ---------- K4 x30: y = 1/(A . x)  (x already inverted unless INV_IN) ----------
// grid 256 blocks x 256 thr; 16 rows/block (4 rows/wave); vector in per-lane regs
template<bool INV_IN>
__global__ __launch_bounds__(256) void mv_kernel(
    const unsigned* __restrict__ Abf, const float* __restrict__ x,
    float* __restrict__ y)
{
    const int blk = blockIdx.x;
    const int lp  = ((blk & 7) << 5) | (blk >> 3);   // XCD-chunked
    const int b   = lp >> 6;
    const int r0  = (lp & 63) << 4;
    const int t = threadIdx.x;
    const int w = t >> 6, l = t & 63;

    // lane l's vector slice: cols 8l..8l+7 and 512+8l..512+8l+7
    const float4* xb = (const float4*)(x + (b << 10));
    float4 x0 = xb[2*l], x1 = xb[2*l+1], x2 = xb[128+2*l], x3 = xb[129+2*l];
    if (INV_IN) {
        x0.x=1.f/x0.x; x0.y=1.f/x0.y; x0.z=1.f/x0.z; x0.w=1.f/x0.w;
        x1.x=1.f/x1.x; x1.y=1.f/x1.y; x1.z=1.f/x1.z; x1.w=1.f/x1.w;
        x2.x=1.f/x2.x; x2.y=1.f/x2.y; x2.z=1.f/x2.z; x2.w=1.f/x2.w;
        x3.x=1.f/x3.x; x3.y=1.f/x3.y; x3.z=1.f/x3.z; x3.w=1.f/x3.w;
    }

    #pragma unroll
    for (int r = 0; r < 4; ++r) {
        const int row = r0 + (w << 2) + r;
        const unsigned* rp = Abf + (((size_t)((b << 10) + row)) << 9);
        const uint4 v0 = ((const uint4*)rp)[l];
        const uint4 v1 = ((const uint4*)rp)[64 + l];
        float a = bflo(v0.x)*x0.x + bfhi(v0.x)*x0.y
                + bflo(v0.y)*x0.z + bfhi(v0.y)*x0.w
                + bflo(v0.z)*x1.x + bfhi(v0.z)*x1.y
                + bflo(v0.w)*x1.z + bfhi(v0.w)*x1.w
                + bflo(v1.x)*x2.x + bfhi(v1.x)*x2.y
                + bflo(v1.y)*x2.z + bfhi(v1.y)*x2.w
                + bflo(v1.z)*x3.x + bfhi(v1.z)*x3.y
                + bflo(v1.w)*x3.z + bfhi(v1.w)*x3.w;
        a = wave_sum(a);
        if (l == 0) y[(b << 10) + row] = 1.0f / a;
    }
}

// ---------- K5: threshold+eps -> A1, A1^T (bf16); rowsums of A1 -> SR2 ----------
// r8,c8 are INVERTED scales (direct multipliers)
__global__ __launch_bounds__(256) void thresh_kernel(
    const unsigned* __restrict__ M0, const unsigned* __restrict__ M0T,
    const float* __restrict__ r8, const float* __restrict__ c8,
    unsigned* __restrict__ A1, unsigned* __restrict__ A1T,
    float* __restrict__ SR2)
{
    const int t = threadIdx.x;
    const int b = blockIdx.x >> 6;
    const int g0 = (blockIdx.x & 63) << 4;
    const int w = t >> 6, l = t & 63;
    const bool doA1 = (w < 2);
    const int wr = doA1 ? w : (w - 2);
    const unsigned* src = doA1 ? M0 : M0T;
    unsigned*       dst = doA1 ? A1 : A1T;
    const float* rowS = doA1 ? r8 : c8;
    const float* colS = doA1 ? c8 : r8;

    const float4* cb = (const float4*)(colS + (b << 10));
    const float4 c0 = cb[2*l], c1 = cb[2*l+1], c2 = cb[128+2*l], c3 = cb[129+2*l];
    const float cm[16] = {c0.x,c0.y,c0.z,c0.w, c1.x,c1.y,c1.z,c1.w,
                          c2.x,c2.y,c2.z,c2.w, c3.x,c3.y,c3.z,c3.w};

    for (int rr = 0; rr < 8; ++rr) {
        const int row = g0 + wr*8 + rr;
        const float ri = rowS[(b << 10) + row];
        const unsigned* rp = src + (((size_t)(b*NN + row)) << 9);
        const uint4 v0 = ((const uint4*)rp)[l];
        const uint4 v1 = ((const uint4*)rp)[64 + l];
        float e[16];
        e[0]=bflo(v0.x); e[1]=bfhi(v0.x); e[2]=bflo(v0.y); e[3]=bfhi(v0.y);
        e[4]=bflo(v0.z); e[5]=bfhi(v0.z); e[6]=bflo(v0.w); e[7]=bfhi(v0.w);
        e[8]=bflo(v1.x); e[9]=bfhi(v1.x); e[10]=bflo(v1.y); e[11]=bfhi(v1.y);
        e[12]=bflo(v1.z); e[13]=bfhi(v1.z); e[14]=bflo(v1.w); e[15]=bfhi(v1.w);
        float s = 0.f;
        #pragma unroll
        for (int j = 0; j < 16; ++j) {
            const float d = e[j] * ri * cm[j];
            e[j] = (d > BASELINE ? d : 0.f) + F_EPS;
            s += e[j];
        }
        uint4 o0, o1;
        o0.x = bf_pack(e[0],e[1]);  o0.y = bf_pack(e[2],e[3]);
        o0.z = bf_pack(e[4],e[5]);  o0.w = bf_pack(e[6],e[7]);
        o1.x = bf_pack(e[8],e[9]);  o1.y = bf_pack(e[10],e[11]);
        o1.z = bf_pack(e[12],e[13]); o1.w = bf_pack(e[14],e[15]);
        unsigned* op = dst + (((size_t)(b*NN + row)) << 9);
        ((uint4*)op)[l] = o0;
        ((uint4*)op)[64 + l] = o1;
        if (doA1) {
            s = wave_sum(s);
            if (l == 0) SR2[b*NN + row] = s;
        }
    }
}

// ---------- K6: final scale + mask -> A (fp32, dout); variance partials ----------
__global__ __launch_bounds__(256) void fin_kernel(
    const unsigned* __restrict__ A1, const float* __restrict__ r8,
    const float* __restrict__ c8, float* __restrict__ reds,
    float* __restrict__ dout)
{
    __shared__ float wred[8];
    const int t = threadIdx.x;
    const int b = blockIdx.x >> 6;
    const int g0 = (blockIdx.x & 63) << 4;
    const int w = t >> 6, l = t & 63;

    const float4* cb = (const float4*)(c8 + (b << 10));
    const float4 c0 = cb[2*l], c1 = cb[2*l+1], c2 = cb[128+2*l], c3 = cb[129+2*l];
    const float cm[16] = {c0.x,c0.y,c0.z,c0.w, c1.x,c1.y,c1.z,c1.w,
                          c2.x,c2.y,c2.z,c2.w, c3.x,c3.y,c3.z,c3.w};

    float s1 = 0.f, s2 = 0.f;
    for (int rr = 0; rr < 4; ++rr) {
        const int row = g0 + w*4 + rr;
        float* Arow = dout + A_OFF + (((size_t)(b*NN + row)) << 10);
        if (row < NUM_IN) {
            const float4 z = make_float4(0.f,0.f,0.f,0.f);
            ((float4*)Arow)[2*l] = z;       ((float4*)Arow)[2*l+1] = z;
            ((float4*)Arow)[128+2*l] = z;   ((float4*)Arow)[129+2*l] = z;
        } else {
            const float ri = r8[(b << 10) + row];
            const unsigned* rp = A1 + (((size_t)(b*NN + row)) << 9);
            const uint4 v0 = ((const uint4*)rp)[l];
            const uint4 v1 = ((const uint4*)rp)[64 + l];
            float e[16];
            e[0]=bflo(v0.x); e[1]=bfhi(v0.x); e[2]=bflo(v0.y); e[3]=bfhi(v0.y);
            e[4]=bflo(v0.z); e[5]=bfhi(v0.z); e[6]=bflo(v0.w); e[7]=bfhi(v0.w);
            e[8]=bflo(v1.x); e[9]=bfhi(v1.x); e[10]=bflo(v1.y); e[11]=bfhi(v1.y);
            e[12]=bflo(v1.z); e[13]=bfhi(v1.z); e[14]=bflo(v1.w); e[15]=bfhi(v1.w);
            #pragma unroll
            for (int j = 0; j < 16; ++j) {
                e[j] = e[j] * ri * cm[j];
                s1 += e[j]; s2 += e[j]*e[j];
            }
            ((float4*)Arow)[2*l]     = make_float4(e[0],e[1],e[2],e[3]);
            ((float4*)Arow)[2*l+1]   = make_float4(e[4],e[5],e[6],e[7]);
            ((float4*)Arow)[128+2*l] = make_float4(e[8],e[9],e[10],e[11]);
            ((float4*)Arow)[129+2*l] = make_float4(e[12],e[13],e[14],e[15]);
        }
    }
    s1 = wave_sum(s1); s2 = wave_sum(s2);
    if (l == 0) { wred[w] = s1; wred[4 + w] = s2; }
    __syncthreads();
    if (t == 0) {
        atomicAdd(&reds[4 + b], wred[0]+wred[1]+wred[2]+wred[3]);
        atomicAdd(&reds[8 + b], wred[4]+wred[5]+wred[6]+wred[7]);
    }
}

// ---------- K7: V = output + relu(0.02 - var) * noise ----------
__global__ __launch_bounds__(256) void vbuild_kernel(
    const float* __restrict__ outp, const float* __restrict__ noise,
    const float* __restrict__ reds, float* __restrict__ V)
{
    const int i = blockIdx.x * 256 + threadIdx.x;   // float4 idx, 131072 total
    const int b = i >> 15;
    const float Mn = 1048576.f;
    const float S1 = reds[4 + b], S2 = reds[8 + b];
    const float var = (S2 - S1*S1/Mn) / (Mn - 1.f);
    const float vd = fmaxf(0.02f - var, 0.f);
    const float4 o = ((const float4*)outp)[i];
    const float4 n = ((const float4*)noise)[i];
    ((float4*)V)[i] = make_float4(o.x + vd*n.x, o.y + vd*n.y,
                                  o.z + vd*n.z, o.w + vd*n.w);
}

// ---------- K8: target = softsign(A @ V); env rows overwrite ----------
__global__ __launch_bounds__(256) void av_kernel(
    const float* __restrict__ A,       // dout + A_OFF (fp32)
    const float* __restrict__ V,
    const float* __restrict__ env,
    float* __restrict__ dout)
{
    const int b = blockIdx.x >> 5;
    const int rb = blockIdx.x & 31;
    const int r0 = rb << 5;
    const int t = threadIdx.x;

    if (r0 < NUM_IN) {
        for (int i = t; i < 32 * ND; i += 256) {
            const int r = i >> 7, d = i & 127;
            dout[((size_t)(b*NN + r0 + r)) * OUT_STRIDE + d] =
                env[(size_t)b * 8192 + (size_t)(r0 + r) * ND + d];
        }
        return;
    }

    __shared__ float As[32][64];
    const int d = t & 127, rg = t >> 7;
    float acc[16];
    #pragma unroll
    for (int k = 0; k < 16; ++k) acc[k] = 0.f;
    const float* Vb = V + (size_t)b * (NN * ND) + d;

    for (int mc = 0; mc < 16; ++mc) {
        #pragma unroll
        for (int j = 0; j < 2; ++j) {
            const int f = 2*t + j, r = f >> 4, c4 = f & 15;
            *(float4*)&As[r][c4*4] =
                *(const float4*)(A + (((size_t)(b*NN + r0 + r)) << 10) + mc*64 + c4*4);
        }
        __syncthreads();
        #pragma unroll 4
        for (int mm4 = 0; mm4 < 16; ++mm4) {
            const float vv0 = Vb[(size_t)(mc*64 + mm4*4 + 0) * ND];
            const float vv1 = Vb[(size_t)(mc*64 + mm4*4 + 1) * ND];
            const float vv2 = Vb[(size_t)(mc*64 + mm4*4 + 2) * ND];
            const float vv3 = Vb[(size_t)(mc*64 + mm4*4 + 3) * ND];
            #pragma unroll
            for (int k = 0; k < 16; ++k) {
                const float4 a = *(const float4*)&As[rg*16 + k][mm4*4];
                acc[k] += a.x*vv0 + a.y*vv1 + a.z*vv2 + a.w*vv3;
            }
        }
        __syncthreads();
    }
    #pragma unroll
    for (int k = 0; k < 16; ++k) {
        const float o = acc[k];
        dout[((size_t)(b*NN + r0 + rg*16 + k)) * OUT_STRIDE + d] = o / (1.f + fabsf(o));
    }
}

extern "C" void kernel_launch(void* const* d_in, const int* in_sizes, int n_in,
                              void* d_out, int out_size, void* d_ws, size_t ws_size,
                              hipStream_t stream)
{
    (void)in_sizes; (void)n_in; (void)out_size; (void)ws_size;
    const float* state = (const float*)d_in[0];
    const float* outp  = (const float*)d_in[1];
    const float* w1    = (const float*)d_in[2];
    const float* w2    = (const float*)d_in[3];
    const float* w3    = (const float*)d_in[4];
    const float* A_ema = (const float*)d_in[5];
    const float* env   = (const float*)d_in[6];
    const float* noise = (const float*)d_in[7];
    float* dout = (float*)d_out;

    // M0 / M0^T live in dout's A-region (dead until fin overwrites it with A)
    unsigned* M0  = (unsigned*)(dout + A_OFF);
    unsigned* M0T = M0 + 2097152;

    // ws layout (floats): Q(512K) K(512K) V(512K) | raw/A1 (2M u) | A1T (2M u) | vecs
    float*    Qg   = (float*)d_ws;
    float*    Kg   = Qg + 524288;
    float*    Vg   = Kg + 524288;
    unsigned* raw  = (unsigned*)(Vg + 524288);   // reused as A1 after emaT
    unsigned* A1   = raw;
    unsigned* A1T  = raw + 2097152;
    float*    SR1  = (float*)(A1T + 2097152);    // [4][1024] sums (atomics)
    float*    reds = SR1 + 4096;                 // [16]
    float*    SC1  = reds + 16;                  // inverted c-vector
    float*    SR2  = SC1 + 4096;                 // sums after thresh
    float*    SC2  = SR2 + 4096;
    float*    RV1  = SC2 + 4096;                 // inverted r-vector (call 1)
    float*    RV2  = RV1 + 4096;                 // inverted r-vector (call 2)

    hipMemsetAsync(SR1, 0, (4096 + 16) * sizeof(float), stream);  // SR1 + reds

    qkp_kernel<<<dim3(NB*NN), dim3(256), 0, stream>>>(
        state, w1, w2, w3, dout, Qg, Kg);

    qk2_kernel<<<dim3(NB*1024), dim3(256), 0, stream>>>(Qg, Kg, raw, reds);

    emaT_kernel<<<dim3(NB*256), dim3(256), 0, stream>>>(
        raw, A_ema, reds, M0, M0T, SR1);

    // Sinkhorn call 1: c1 = 1/(M0T . (1/SR1)); then alternate. 15 matvecs.
    mv_kernel<true ><<<dim3(256), dim3(256), 0, stream>>>(M0T, SR1, SC1);
    for (int k = 1; k < 15; ++k) {
        if (k & 1)
            mv_kernel<false><<<dim3(256), dim3(256), 0, stream>>>(M0, SC1, RV1);
        else
            mv_kernel<false><<<dim3(256), dim3(256), 0, stream>>>(M0T, RV1, SC1);
    }
    // after loop: RV1 = r8 (inv), SC1 = c8 (inv)

    thresh_kernel<<<dim3(NB*64), dim3(256), 0, stream>>>(
        M0, M0T, RV1, SC1, A1, A1T, SR2);

    // Sinkhorn call 2
    mv_kernel<true ><<<dim3(256), dim3(256), 0, stream>>>(A1T, SR2, SC2);
    for (int k = 1; k < 15; ++k) {
        if (k & 1)
            mv_kernel<false><<<dim3(256), dim3(256), 0, stream>>>(A1, SC2, RV2);
        else
            mv_kernel<false><<<dim3(256), dim3(256), 0, stream>>>(A1T, RV2, SC2);
    }

    fin_kernel<<<dim3(NB*64), dim3(256), 0, stream>>>(A1, RV2, SC2, reds, dout);

    vbuild_kernel<<<dim3(512), dim3(256), 0, stream>>>(outp, noise, reds, Vg);

    av_kernel<<<dim3(NB*32), dim3(256), 0, stream>>>(dout + A_OFF, Vg, env, dout);
}

// Round 6
// 422.101 us; speedup vs baseline: 1.9460x; 1.1918x over previous
//
#include <hip/hip_runtime.h>
#include <math.h>

#define NB 4
#define NN 1024
#define ND 128
#define NUM_IN 64
#define F_EPS 1e-8f
#define BT_SCALE 1.8477590650225735f      // sqrt(2+sqrt(2))
#define INV_SQRT_D 0.08838834764831844f   // 1/sqrt(128)
#define BASELINE (1.0f/1025.0f)
#define OUT_STRIDE 256
#define A_OFF 1048576                     // floats: NB*NN*OUT_STRIDE

__device__ __forceinline__ float buntanh_f(float x) {
    return BT_SCALE * (0.5f * x + 0.5f * tanhf(x));
}
__device__ __forceinline__ float wave_sum(float v) {
    #pragma unroll
    for (int off = 32; off > 0; off >>= 1) v += __shfl_xor(v, off, 64);
    return v;
}
__device__ __forceinline__ float bflo(unsigned u) { return __uint_as_float(u << 16); }
__device__ __forceinline__ float bfhi(unsigned u) { return __uint_as_float(u & 0xffff0000u); }
__device__ __forceinline__ unsigned bf_rne(float f) {
    unsigned x = __float_as_uint(f);
    return (x + 0x7fffu + ((x >> 16) & 1u)) >> 16;
}
__device__ __forceinline__ unsigned bf_pack(float lo, float hi) {
    return bf_rne(lo) | (bf_rne(hi) << 16);
}

typedef float f32x4 __attribute__((ext_vector_type(4)));
__device__ __forceinline__ float4 ntload4(const float4* p) {
    f32x4 v = __builtin_nontemporal_load((const f32x4*)p);
    return make_float4(v.x, v.y, v.z, v.w);
}

// ---------- K1: per-node matvecs (w1,w2,w3 fused) -> prediction, K, Q ----------
__global__ __launch_bounds__(256, 6) void qkp_kernel(
    const float* __restrict__ state,
    const float* __restrict__ w1,
    const float* __restrict__ w2,
    const float* __restrict__ w3,
    float* __restrict__ dout,
    float* __restrict__ Qg,
    float* __restrict__ Kg)
{
    const int blk = blockIdx.x;
    const int node = ((blk & 7) << 9) | (blk >> 3);   // XCD-chunked

    __shared__ float s_state[ND];
    __shared__ float4 red[3][8][32];

    const int t = threadIdx.x;
    if (t < 32) ((float4*)s_state)[t] =
        ((const float4*)(state + ((size_t)node << 7)))[t];
    __syncthreads();

    const int g = t >> 5, m = t & 31;

    auto do_mat = [&](const float* wbase, int q) {
        const float4* w4 = (const float4*)(wbase + ((size_t)node << 14));
        float4 wv[8];
        float4 acc = make_float4(0.f, 0.f, 0.f, 0.f);
        #pragma unroll
        for (int i = 0; i < 8; ++i) wv[i] = ntload4(&w4[i*256 + t]);
        #pragma unroll
        for (int i = 0; i < 8; ++i) {
            const float s = s_state[i*8 + g];
            acc.x += s*wv[i].x; acc.y += s*wv[i].y;
            acc.z += s*wv[i].z; acc.w += s*wv[i].w;
        }
        #pragma unroll
        for (int i = 0; i < 8; ++i) wv[i] = ntload4(&w4[(8+i)*256 + t]);
        #pragma unroll
        for (int i = 0; i < 8; ++i) {
            const float s = s_state[(8+i)*8 + g];
            acc.x += s*wv[i].x; acc.y += s*wv[i].y;
            acc.z += s*wv[i].z; acc.w += s*wv[i].w;
        }
        red[q][g][m] = acc;
    };
    do_mat(w1, 0);
    do_mat(w2, 1);
    do_mat(w3, 2);
    __syncthreads();

    if (t < 96) {
        const int q = t >> 5, mm = t & 31;
        float4 o = red[q][0][mm];
        #pragma unroll
        for (int gg = 1; gg < 8; ++gg) {
            const float4 r = red[q][gg][mm];
            o.x += r.x; o.y += r.y; o.z += r.z; o.w += r.w;
        }
        o.x = buntanh_f(o.x); o.y = buntanh_f(o.y);
        o.z = buntanh_f(o.z); o.w = buntanh_f(o.w);
        if (q == 0) {
            *(float4*)(dout + (size_t)node * OUT_STRIDE + ND + 4*mm) = o;   // prediction
        } else {
            float* base = (q == 1) ? Kg : Qg;                               // w2->K, w3->Q
            *(float4*)(base + ((size_t)node << 7) + 4*mm) = o;
        }
    }
}

// ---------- K2: raw_A = Q K^T * inv_sqrt_d -> raw (bf16); ssq atomics ----------
__global__ __launch_bounds__(256) void qk2_kernel(
    const float* __restrict__ Qg, const float* __restrict__ Kg,
    unsigned* __restrict__ rawbf, float* __restrict__ reds)
{
    const int b = blockIdx.x >> 10;
    const int tile = blockIdx.x & 1023;
    const int tr = tile >> 5, tc = tile & 31;

    __shared__ float Qs[32][132];
    __shared__ float Ks[32][136];
    __shared__ float wr4[4];

    const int t = threadIdx.x;
    for (int i = t; i < 1024; i += 256) {
        const int r = i >> 5, q = i & 31;
        *(float4*)&Qs[r][q*4] = *(const float4*)(Qg + (((size_t)(b*NN + tr*32 + r)) << 7) + q*4);
        *(float4*)&Ks[r][q*4] = *(const float4*)(Kg + (((size_t)(b*NN + tc*32 + r)) << 7) + q*4);
    }
    __syncthreads();

    const int ty = t >> 4;        // rows ty, ty+16
    const int tx = t & 15;        // cols 2tx, 2tx+1
    float a00=0.f, a01=0.f, a10=0.f, a11=0.f;
    #pragma unroll
    for (int dq = 0; dq < 32; ++dq) {
        const float4 q0 = *(const float4*)&Qs[ty][dq*4];
        const float4 q1 = *(const float4*)&Qs[ty+16][dq*4];
        const float4 k0 = *(const float4*)&Ks[2*tx][dq*4];
        const float4 k1 = *(const float4*)&Ks[2*tx+1][dq*4];
        a00 += q0.x*k0.x + q0.y*k0.y + q0.z*k0.z + q0.w*k0.w;
        a01 += q0.x*k1.x + q0.y*k1.y + q0.z*k1.z + q0.w*k1.w;
        a10 += q1.x*k0.x + q1.y*k0.y + q1.z*k0.z + q1.w*k0.w;
        a11 += q1.x*k1.x + q1.y*k1.y + q1.z*k1.z + q1.w*k1.w;
    }
    a00 *= INV_SQRT_D; a01 *= INV_SQRT_D; a10 *= INV_SQRT_D; a11 *= INV_SQRT_D;

    unsigned* r0p = rawbf + (((size_t)(b*NN + tr*32 + ty)) << 9) + tc*16;
    unsigned* r1p = rawbf + (((size_t)(b*NN + tr*32 + ty + 16)) << 9) + tc*16;
    r0p[tx] = bf_pack(a00, a01);
    r1p[tx] = bf_pack(a10, a11);

    float ssq = a00*a00 + a01*a01 + a10*a10 + a11*a11;
    ssq = wave_sum(ssq);
    if ((t & 63) == 0) wr4[t >> 6] = ssq;
    __syncthreads();
    if (t == 0) atomicAdd(&reds[b], wr4[0]+wr4[1]+wr4[2]+wr4[3]);
}

// ---------- K3: EMA+mask+eps transform; write M0, M0^T (bf16); rowsum atomics ----------
__global__ __launch_bounds__(256) void emaT_kernel(
    const unsigned* __restrict__ rawbf, const float* __restrict__ A_ema,
    const float* __restrict__ reds,
    unsigned* __restrict__ M0, unsigned* __restrict__ M0T,
    float* __restrict__ SR)
{
    const int b = blockIdx.x >> 8;
    const int tile = blockIdx.x & 255;
    const int tr = tile >> 4, tc = tile & 15;
    const int R0 = tr << 6, C0 = tc << 6;

    __shared__ float st[64][65];
    __shared__ float s_part[64][5];

    const int t = threadIdx.x;
    const int r = t >> 2, q = t & 3;
    const int row = R0 + r;
    const float scale = rsqrtf(reds[b] * (1.0f/1048576.0f) + F_EPS);

    const unsigned* rawrow = rawbf + (((size_t)(b*NN + row)) << 9) + tc*8*4;
    const uint4 u0 = ((const uint4*)rawrow)[q*2];
    const uint4 u1 = ((const uint4*)rawrow)[q*2 + 1];
    float rv[16];
    rv[0]=bflo(u0.x); rv[1]=bfhi(u0.x); rv[2]=bflo(u0.y); rv[3]=bfhi(u0.y);
    rv[4]=bflo(u0.z); rv[5]=bfhi(u0.z); rv[6]=bflo(u0.w); rv[7]=bfhi(u0.w);
    rv[8]=bflo(u1.x); rv[9]=bfhi(u1.x); rv[10]=bflo(u1.y); rv[11]=bfhi(u1.y);
    rv[12]=bflo(u1.z); rv[13]=bfhi(u1.z); rv[14]=bflo(u1.w); rv[15]=bfhi(u1.w);

    const float* emarow = A_ema + (((size_t)(b*NN + row)) << 10) + C0 + q*16;
    float s = 0.f;
    #pragma unroll
    for (int j = 0; j < 4; ++j) {
        const float4 e = ((const float4*)emarow)[j];
        float ev[4] = {e.x, e.y, e.z, e.w};
        #pragma unroll
        for (int k = 0; k < 4; ++k) {
            const int e_idx = j*4 + k;
            const int c = C0 + q*16 + e_idx;
            float em = ev[k];
            if (row == NUM_IN && c < NUM_IN) em += 3.0f / NUM_IN;
            float v = em * 0.99f + rv[e_idx] * scale * 0.01f;
            if (row < NUM_IN) v = 0.f;
            v = fmaxf(v, 0.f) + F_EPS;
            rv[e_idx] = v;
            st[r][q*16 + e_idx] = v;
            s += v;
        }
    }
    s_part[r][q] = s;

    unsigned* m0row = M0 + (((size_t)(b*NN + row)) << 9) + tc*8*4;
    uint4 o0, o1;
    o0.x = bf_pack(rv[0],rv[1]);  o0.y = bf_pack(rv[2],rv[3]);
    o0.z = bf_pack(rv[4],rv[5]);  o0.w = bf_pack(rv[6],rv[7]);
    o1.x = bf_pack(rv[8],rv[9]);  o1.y = bf_pack(rv[10],rv[11]);
    o1.z = bf_pack(rv[12],rv[13]); o1.w = bf_pack(rv[14],rv[15]);
    ((uint4*)m0row)[q*2]     = o0;
    ((uint4*)m0row)[q*2 + 1] = o1;
    __syncthreads();

    if (t < 64) {
        const float rs = s_part[t][0] + s_part[t][1] + s_part[t][2] + s_part[t][3];
        atomicAdd(&SR[b*NN + R0 + t], rs);
    }

    const int cT = t >> 2;
    float tv[16];
    #pragma unroll
    for (int k = 0; k < 16; ++k) tv[k] = st[q*16 + k][cT];
    uint4 w0, w1;
    w0.x = bf_pack(tv[0],tv[1]);  w0.y = bf_pack(tv[2],tv[3]);
    w0.z = bf_pack(tv[4],tv[5]);  w0.w = bf_pack(tv[6],tv[7]);
    w1.x = bf_pack(tv[8],tv[9]);  w1.y = bf_pack(tv[10],tv[11]);
    w1.z = bf_pack(tv[12],tv[13]); w1.w = bf_pack(tv[14],tv[15]);
    unsigned* mtrow = M0T + (((size_t)(b*NN + C0 + cT)) << 9) + tr*8*4;
    ((uint4*)mtrow)[q*2]     = w0;
    ((uint4*)mtrow)[q*2 + 1] = w1;
}

// ---------- K4 x30: y = 1/(A . x)  (x already inverted unless INV_IN) ----------
template<bool INV_IN>
__global__ __launch_bounds__(256) void mv_kernel(
    const unsigned* __restrict__ Abf, const float* __restrict__ x,
    float* __restrict__ y)
{
    const int blk = blockIdx.x;
    const int lp  = ((blk & 7) << 5) | (blk >> 3);   // XCD-chunked
    const int b   = lp >> 6;
    const int r0  = (lp & 63) << 4;
    const int t = threadIdx.x;
    const int w = t >> 6, l = t & 63;

    const float4* xb = (const float4*)(x + (b << 10));
    float4 x0 = xb[2*l], x1 = xb[2*l+1], x2 = xb[128+2*l], x3 = xb[129+2*l];
    if (INV_IN) {
        x0.x=1.f/x0.x; x0.y=1.f/x0.y; x0.z=1.f/x0.z; x0.w=1.f/x0.w;
        x1.x=1.f/x1.x; x1.y=1.f/x1.y; x1.z=1.f/x1.z; x1.w=1.f/x1.w;
        x2.x=1.f/x2.x; x2.y=1.f/x2.y; x2.z=1.f/x2.z; x2.w=1.f/x2.w;
        x3.x=1.f/x3.x; x3.y=1.f/x3.y; x3.z=1.f/x3.z; x3.w=1.f/x3.w;
    }

    #pragma unroll
    for (int r = 0; r < 4; ++r) {
        const int row = r0 + (w << 2) + r;
        const unsigned* rp = Abf + (((size_t)((b << 10) + row)) << 9);
        const uint4 v0 = ((const uint4*)rp)[l];
        const uint4 v1 = ((const uint4*)rp)[64 + l];
        float a = bflo(v0.x)*x0.x + bfhi(v0.x)*x0.y
                + bflo(v0.y)*x0.z + bfhi(v0.y)*x0.w
                + bflo(v0.z)*x1.x + bfhi(v0.z)*x1.y
                + bflo(v0.w)*x1.z + bfhi(v0.w)*x1.w
                + bflo(v1.x)*x2.x + bfhi(v1.x)*x2.y
                + bflo(v1.y)*x2.z + bfhi(v1.y)*x2.w
                + bflo(v1.z)*x3.x + bfhi(v1.z)*x3.y
                + bflo(v1.w)*x3.z + bfhi(v1.w)*x3.w;
        a = wave_sum(a);
        if (l == 0) y[(b << 10) + row] = 1.0f / a;
    }
}

// ---------- K5: threshold+eps -> A1, A1^T (bf16); rowsums of A1 -> SR2 ----------
__global__ __launch_bounds__(256) void thresh_kernel(
    const unsigned* __restrict__ M0, const unsigned* __restrict__ M0T,
    const float* __restrict__ r8, const float* __restrict__ c8,
    unsigned* __restrict__ A1, unsigned* __restrict__ A1T,
    float* __restrict__ SR2)
{
    const int t = threadIdx.x;
    const int b = blockIdx.x >> 6;
    const int g0 = (blockIdx.x & 63) << 4;
    const int w = t >> 6, l = t & 63;
    const bool doA1 = (w < 2);
    const int wr = doA1 ? w : (w - 2);
    const unsigned* src = doA1 ? M0 : M0T;
    unsigned*       dst = doA1 ? A1 : A1T;
    const float* rowS = doA1 ? r8 : c8;
    const float* colS = doA1 ? c8 : r8;

    const float4* cb = (const float4*)(colS + (b << 10));
    const float4 c0 = cb[2*l], c1 = cb[2*l+1], c2 = cb[128+2*l], c3 = cb[129+2*l];
    const float cm[16] = {c0.x,c0.y,c0.z,c0.w, c1.x,c1.y,c1.z,c1.w,
                          c2.x,c2.y,c2.z,c2.w, c3.x,c3.y,c3.z,c3.w};

    for (int rr = 0; rr < 8; ++rr) {
        const int row = g0 + wr*8 + rr;
        const float ri = rowS[(b << 10) + row];
        const unsigned* rp = src + (((size_t)(b*NN + row)) << 9);
        const uint4 v0 = ((const uint4*)rp)[l];
        const uint4 v1 = ((const uint4*)rp)[64 + l];
        float e[16];
        e[0]=bflo(v0.x); e[1]=bfhi(v0.x); e[2]=bflo(v0.y); e[3]=bfhi(v0.y);
        e[4]=bflo(v0.z); e[5]=bfhi(v0.z); e[6]=bflo(v0.w); e[7]=bfhi(v0.w);
        e[8]=bflo(v1.x); e[9]=bfhi(v1.x); e[10]=bflo(v1.y); e[11]=bfhi(v1.y);
        e[12]=bflo(v1.z); e[13]=bfhi(v1.z); e[14]=bflo(v1.w); e[15]=bfhi(v1.w);
        float s = 0.f;
        #pragma unroll
        for (int j = 0; j < 16; ++j) {
            const float d = e[j] * ri * cm[j];
            e[j] = (d > BASELINE ? d : 0.f) + F_EPS;
            s += e[j];
        }
        uint4 o0, o1;
        o0.x = bf_pack(e[0],e[1]);  o0.y = bf_pack(e[2],e[3]);
        o0.z = bf_pack(e[4],e[5]);  o0.w = bf_pack(e[6],e[7]);
        o1.x = bf_pack(e[8],e[9]);  o1.y = bf_pack(e[10],e[11]);
        o1.z = bf_pack(e[12],e[13]); o1.w = bf_pack(e[14],e[15]);
        unsigned* op = dst + (((size_t)(b*NN + row)) << 9);
        ((uint4*)op)[l] = o0;
        ((uint4*)op)[64 + l] = o1;
        if (doA1) {
            s = wave_sum(s);
            if (l == 0) SR2[b*NN + row] = s;
        }
    }
}

// ---------- K6: final scale + mask -> A (fp32, dout); variance partials ----------
__global__ __launch_bounds__(256) void fin_kernel(
    const unsigned* __restrict__ A1, const float* __restrict__ r8,
    const float* __restrict__ c8, float* __restrict__ reds,
    float* __restrict__ dout)
{
    __shared__ float wred[8];
    const int t = threadIdx.x;
    const int b = blockIdx.x >> 6;
    const int g0 = (blockIdx.x & 63) << 4;
    const int w = t >> 6, l = t & 63;

    const float4* cb = (const float4*)(c8 + (b << 10));
    const float4 c0 = cb[2*l], c1 = cb[2*l+1], c2 = cb[128+2*l], c3 = cb[129+2*l];
    const float cm[16] = {c0.x,c0.y,c0.z,c0.w, c1.x,c1.y,c1.z,c1.w,
                          c2.x,c2.y,c2.z,c2.w, c3.x,c3.y,c3.z,c3.w};

    float s1 = 0.f, s2 = 0.f;
    for (int rr = 0; rr < 4; ++rr) {
        const int row = g0 + w*4 + rr;
        float* Arow = dout + A_OFF + (((size_t)(b*NN + row)) << 10);
        if (row < NUM_IN) {
            const float4 z = make_float4(0.f,0.f,0.f,0.f);
            ((float4*)Arow)[2*l] = z;       ((float4*)Arow)[2*l+1] = z;
            ((float4*)Arow)[128+2*l] = z;   ((float4*)Arow)[129+2*l] = z;
        } else {
            const float ri = r8[(b << 10) + row];
            const unsigned* rp = A1 + (((size_t)(b*NN + row)) << 9);
            const uint4 v0 = ((const uint4*)rp)[l];
            const uint4 v1 = ((const uint4*)rp)[64 + l];
            float e[16];
            e[0]=bflo(v0.x); e[1]=bfhi(v0.x); e[2]=bflo(v0.y); e[3]=bfhi(v0.y);
            e[4]=bflo(v0.z); e[5]=bfhi(v0.z); e[6]=bflo(v0.w); e[7]=bfhi(v0.w);
            e[8]=bflo(v1.x); e[9]=bfhi(v1.x); e[10]=bflo(v1.y); e[11]=bfhi(v1.y);
            e[12]=bflo(v1.z); e[13]=bfhi(v1.z); e[14]=bflo(v1.w); e[15]=bfhi(v1.w);
            #pragma unroll
            for (int j = 0; j < 16; ++j) {
                e[j] = e[j] * ri * cm[j];
                s1 += e[j]; s2 += e[j]*e[j];
            }
            ((float4*)Arow)[2*l]     = make_float4(e[0],e[1],e[2],e[3]);
            ((float4*)Arow)[2*l+1]   = make_float4(e[4],e[5],e[6],e[7]);
            ((float4*)Arow)[128+2*l] = make_float4(e[8],e[9],e[10],e[11]);
            ((float4*)Arow)[129+2*l] = make_float4(e[12],e[13],e[14],e[15]);
        }
    }
    s1 = wave_sum(s1); s2 = wave_sum(s2);
    if (l == 0) { wred[w] = s1; wred[4 + w] = s2; }
    __syncthreads();
    if (t == 0) {
        atomicAdd(&reds[4 + b], wred[0]+wred[1]+wred[2]+wred[3]);
        atomicAdd(&reds[8 + b], wred[4]+wred[5]+wred[6]+wred[7]);
    }
}

// ---------- K7: V = output + relu(0.02 - var) * noise ----------
__global__ __launch_bounds__(256) void vbuild_kernel(
    const float* __restrict__ outp, const float* __restrict__ noise,
    const float* __restrict__ reds, float* __restrict__ V)
{
    const int i = blockIdx.x * 256 + threadIdx.x;   // float4 idx, 131072 total
    const int b = i >> 15;
    const float Mn = 1048576.f;
    const float S1 = reds[4 + b], S2 = reds[8 + b];
    const float var = (S2 - S1*S1/Mn) / (Mn - 1.f);
    const float vd = fmaxf(0.02f - var, 0.f);
    const float4 o = ((const float4*)outp)[i];
    const float4 n = ((const float4*)noise)[i];
    ((float4*)V)[i] = make_float4(o.x + vd*n.x, o.y + vd*n.y,
                                  o.z + vd*n.z, o.w + vd*n.w);
}

// ---------- K8a: split-K partial GEMM  P[ks][b][ridx][d] = A-chunk @ V-chunk ----------
// grid: 4 b x 60 rowtiles(16 rows) x 4 ksplit = 960 blocks x 256 thr
__global__ __launch_bounds__(256) void av_part(
    const float* __restrict__ A,       // dout + A_OFF (fp32)
    const float* __restrict__ V,
    float* __restrict__ P)
{
    const int bid = blockIdx.x;
    const int ks = bid & 3;
    const int rt = (bid >> 2) % 60;
    const int b  = bid / 240;
    const int r0 = NUM_IN + rt * 16;
    const int mc0 = ks << 8;
    const int t = threadIdx.x;
    const int d = t & 127, rg = t >> 7;
    const int rowb = r0 + rg*8;

    float acc[8] = {0.f,0.f,0.f,0.f,0.f,0.f,0.f,0.f};
    const float* Vb = V + ((size_t)b << 17) + ((size_t)mc0 << 7) + d;
    const float* Ab = A + (((size_t)(b*NN + rowb)) << 10) + mc0;

    #pragma unroll 4
    for (int mq = 0; mq < 64; ++mq) {
        const float v0 = Vb[(mq*4 + 0) << 7];
        const float v1 = Vb[(mq*4 + 1) << 7];
        const float v2 = Vb[(mq*4 + 2) << 7];
        const float v3 = Vb[(mq*4 + 3) << 7];
        #pragma unroll
        for (int k = 0; k < 8; ++k) {
            const float4 a = *(const float4*)(Ab + ((size_t)k << 10) + mq*4);
            acc[k] += a.x*v0 + a.y*v1 + a.z*v2 + a.w*v3;
        }
    }
    #pragma unroll
    for (int k = 0; k < 8; ++k) {
        const int ridx = rt*16 + rg*8 + k;
        P[(((size_t)(ks*NB + b)) * 960 + ridx) * 128 + d] = acc[k];
    }
}

// ---------- K8b: sum partials + softsign -> dout; env rows overwrite ----------
// grid: 128 env blocks + 1920 sum blocks
__global__ __launch_bounds__(256) void av_fin(
    const float* __restrict__ P, const float* __restrict__ env,
    float* __restrict__ dout)
{
    const int t = threadIdx.x;
    int bid = blockIdx.x;
    if (bid < 128) {
        const int idx = bid*256 + t;         // 0..32767 over [4][8192]
        const int b = idx >> 13, off = idx & 8191;
        const int r = off >> 7, d = off & 127;
        dout[((size_t)(b*NN + r)) * OUT_STRIDE + d] = env[idx];
        return;
    }
    bid -= 128;
    const int idx = bid*256 + t;             // 0..491519 over [4][960][128]
    const int d = idx & 127;
    const int rd = idx >> 7;                 // b*960 + ridx
    const int b = rd / 960;
    const int ridx = rd - b*960;
    const float s = P[idx] + P[idx + 491520] + P[idx + 2*491520] + P[idx + 3*491520];
    dout[((size_t)(b*NN + NUM_IN + ridx)) * OUT_STRIDE + d] = s / (1.f + fabsf(s));
}

extern "C" void kernel_launch(void* const* d_in, const int* in_sizes, int n_in,
                              void* d_out, int out_size, void* d_ws, size_t ws_size,
                              hipStream_t stream)
{
    (void)in_sizes; (void)n_in; (void)out_size; (void)ws_size;
    const float* state = (const float*)d_in[0];
    const float* outp  = (const float*)d_in[1];
    const float* w1    = (const float*)d_in[2];
    const float* w2    = (const float*)d_in[3];
    const float* w3    = (const float*)d_in[4];
    const float* A_ema = (const float*)d_in[5];
    const float* env   = (const float*)d_in[6];
    const float* noise = (const float*)d_in[7];
    float* dout = (float*)d_out;

    // M0 / M0^T live in dout's A-region (dead until fin overwrites it with A)
    unsigned* M0  = (unsigned*)(dout + A_OFF);
    unsigned* M0T = M0 + 2097152;

    // ws layout (floats): Q(512K) K(512K) V(512K) | raw/A1 (2M u) | A1T (2M u) | vecs
    float*    Qg   = (float*)d_ws;
    float*    Kg   = Qg + 524288;
    float*    Vg   = Kg + 524288;
    unsigned* raw  = (unsigned*)(Vg + 524288);   // reused as A1 after emaT
    unsigned* A1   = raw;
    unsigned* A1T  = raw + 2097152;
    float*    Pp   = (float*)A1T;                // av partials reuse A1T (dead by then)
    float*    SR1  = (float*)(A1T + 2097152);    // [4][1024] sums (atomics)
    float*    reds = SR1 + 4096;                 // [16]
    float*    SC1  = reds + 16;                  // inverted c-vector
    float*    SR2  = SC1 + 4096;                 // sums after thresh
    float*    SC2  = SR2 + 4096;
    float*    RV1  = SC2 + 4096;                 // inverted r-vector (call 1)
    float*    RV2  = RV1 + 4096;                 // inverted r-vector (call 2)

    hipMemsetAsync(SR1, 0, (4096 + 16) * sizeof(float), stream);  // SR1 + reds

    qkp_kernel<<<dim3(NB*NN), dim3(256), 0, stream>>>(
        state, w1, w2, w3, dout, Qg, Kg);

    qk2_kernel<<<dim3(NB*1024), dim3(256), 0, stream>>>(Qg, Kg, raw, reds);

    emaT_kernel<<<dim3(NB*256), dim3(256), 0, stream>>>(
        raw, A_ema, reds, M0, M0T, SR1);

    // Sinkhorn call 1: c1 = 1/(M0T . (1/SR1)); then alternate. 15 matvecs.
    mv_kernel<true ><<<dim3(256), dim3(256), 0, stream>>>(M0T, SR1, SC1);
    for (int k = 1; k < 15; ++k) {
        if (k & 1)
            mv_kernel<false><<<dim3(256), dim3(256), 0, stream>>>(M0, SC1, RV1);
        else
            mv_kernel<false><<<dim3(256), dim3(256), 0, stream>>>(M0T, RV1, SC1);
    }
    // after loop: RV1 = r8 (inv), SC1 = c8 (inv)

    thresh_kernel<<<dim3(NB*64), dim3(256), 0, stream>>>(
        M0, M0T, RV1, SC1, A1, A1T, SR2);

    // Sinkhorn call 2
    mv_kernel<true ><<<dim3(256), dim3(256), 0, stream>>>(A1T, SR2, SC2);
    for (int k = 1; k < 15; ++k) {
        if (k & 1)
            mv_kernel<false><<<dim3(256), dim3(256), 0, stream>>>(A1, SC2, RV2);
        else
            mv_kernel<false><<<dim3(256), dim3(256), 0, stream>>>(A1T, RV2, SC2);
    }

    fin_kernel<<<dim3(NB*64), dim3(256), 0, stream>>>(A1, RV2, SC2, reds, dout);

    vbuild_kernel<<<dim3(512), dim3(256), 0, stream>>>(outp, noise, reds, Vg);

    av_part<<<dim3(960), dim3(256), 0, stream>>>(dout + A_OFF, Vg, Pp);

    av_fin<<<dim3(2048), dim3(256), 0, stream>>>(Pp, env, dout);
}